// Round 5
// baseline (965.974 us; speedup 1.0000x reference)
//
#include <hip/hip_runtime.h>
#include <hip/hip_fp16.h>

#define NN 50000
#define NE 800000
#define HIDD 128
#define FEAT_E 16
#define NGRAPH 8
#define CAP 64
#define GATBLK 1280     // persistent blocks (5120 waves)
#define NQPART 8        // work-queue partitions
#define NPART (NN / NQPART)  // 6250 nodes per partition
#define QSTRIDE 32      // ints per counter (128B padding)

typedef __attribute__((ext_vector_type(2))) _Float16 half2_t;
typedef __attribute__((ext_vector_type(8))) _Float16 half8_t;
typedef __attribute__((ext_vector_type(4))) float floatx4;

// Layout note: node_linear's MFMA epilogue computes, for tile t and lane
// arow, output channel oc(t,arow) = arow*8 + t (set by column-ordering the
// staged weight matrix wtg). Lane arow therefore holds channels
// [arow*8, arow*8+8) contiguously -> ONE half8 store in STANDARD layout,
// and the fused kernel's lane l16 owns 8 contiguous same-head channels
// (head = l16>>2). No permutation anywhere else in the pipeline.

// ---- order-preserving float<->uint encoding for atomicMax on floats ----
__device__ __forceinline__ unsigned int fenc(float f) {
  unsigned int u = __float_as_uint(f);
  return (u & 0x80000000u) ? ~u : (u | 0x80000000u);
}
__device__ __forceinline__ float fdec(unsigned int u) {
  if (u == 0u) return 0.0f;
  float f = (u & 0x80000000u) ? __uint_as_float(u & 0x7fffffffu)
                              : __uint_as_float(~u);
  return __builtin_isfinite(f) ? f : 0.0f;
}

__device__ __forceinline__ half8_t splat8(_Float16 v) {
  return (half8_t){v, v, v, v, v, v, v, v};
}
__device__ __forceinline__ half8_t hmax8(half8_t a, half8_t b) {
#if __has_builtin(__builtin_elementwise_max)
  return __builtin_elementwise_max(a, b);
#else
  half8_t r;
#pragma unroll
  for (int i = 0; i < 8; ++i) r[i] = a[i] > b[i] ? a[i] : b[i];
  return r;
#endif
}
__device__ __forceinline__ float dot_att(half8_t lk, half2_t t01, half2_t t23,
                                         half2_t t45, half2_t t67) {
#if __has_builtin(__builtin_amdgcn_fdot2)
  float p = __builtin_amdgcn_fdot2((half2_t){lk[0], lk[1]}, t01, 0.f, false);
  p = __builtin_amdgcn_fdot2((half2_t){lk[2], lk[3]}, t23, p, false);
  p = __builtin_amdgcn_fdot2((half2_t){lk[4], lk[5]}, t45, p, false);
  p = __builtin_amdgcn_fdot2((half2_t){lk[6], lk[7]}, t67, p, false);
  return p;
#else
  float p = 0.f;
  p += (float)lk[0] * (float)t01[0] + (float)lk[1] * (float)t01[1];
  p += (float)lk[2] * (float)t23[0] + (float)lk[3] * (float)t23[1];
  p += (float)lk[4] * (float)t45[0] + (float)lk[5] * (float)t45[1];
  p += (float)lk[6] * (float)t67[0] + (float)lk[7] * (float)t67[1];
  return p;
#endif
}

// ---- prep: wtg[which(2)][r(128)][col(128)] fp16, col = k ^ ((r&7)<<3).
// Row r of the staged matrix holds W[:, oc_src(r)] with
// oc_src(r) = (r&15)*8 + (r>>4)  -> identity output layout (see note above).
__global__ void prep_wt_k(const float* __restrict__ Wl, const float* __restrict__ Wr,
                          _Float16* __restrict__ wtg) {
  const int r = blockIdx.x & 127;
  const int which = blockIdx.x >> 7;
  const int k = threadIdx.x;  // 0..127
  const float* W = which ? Wr : Wl;
  const int oc_src = (r & 15) * 8 + (r >> 4);
  const int col = k ^ ((r & 7) << 3);
  wtg[(which * 128 + r) * 128 + col] = (_Float16)W[k * 128 + oc_src];
}

// ---- A-fragment loaders (fp32 input layer 1, fp16 layer 2) ----
__device__ __forceinline__ half8_t load_a8(const _Float16* p) {
  return *(const half8_t*)p;
}
__device__ __forceinline__ half8_t load_a8(const float* p) {
  const float4 f0 = *(const float4*)p;
  const float4 f1 = *(const float4*)(p + 4);
  return (half8_t){(_Float16)f0.x, (_Float16)f0.y, (_Float16)f0.z, (_Float16)f0.w,
                   (_Float16)f1.x, (_Float16)f1.y, (_Float16)f1.z, (_Float16)f1.w};
}

// ---- node linear via MFMA, LDS-staged swizzled weights ----
// grid (ceil(NN/64), 2): blockIdx.y = 0 -> xl (Wl), 1 -> xr (Wr).
// block 256 = 4 waves; wave = 16 nodes x 128 outs (8 tiles, 32 acc VGPR).
// Epilogue: lane arow stores channels [arow*8, arow*8+8) as one half8.
template <typename TIN>
__global__ __launch_bounds__(256) void node_linear_mfma_k(
    const TIN* __restrict__ x, const _Float16* __restrict__ wtg,
    const float* __restrict__ bl, const float* __restrict__ br,
    _Float16* __restrict__ xl16, _Float16* __restrict__ xr16) {
  __shared__ _Float16 wt[128 * 128];  // 32 KB
  const int tid = threadIdx.x;
  const int which = blockIdx.y;
  const _Float16* wsrc = wtg + which * (128 * 128);
  const float* bias128 = which ? br : bl;
  _Float16* out = which ? xr16 : xl16;
  {
    const half8_t* src = (const half8_t*)wsrc;
    half8_t* dstl = (half8_t*)wt;
#pragma unroll
    for (int it = 0; it < 8; ++it)
      dstl[it * 256 + tid] = src[it * 256 + tid];
  }
  __syncthreads();

  const int wv = tid >> 6, lane = tid & 63;
  const int arow = lane & 15, kq = lane >> 4;
  const int nbase = blockIdx.x * 64 + wv * 16;
  int nload = nbase + arow;
  if (nload >= NN) nload = NN - 1;
  floatx4 acc[8];
#pragma unroll
  for (int t = 0; t < 8; ++t) acc[t] = (floatx4){0.f, 0.f, 0.f, 0.f};
#pragma unroll
  for (int kb = 0; kb < 4; ++kb) {
    const half8_t a = load_a8(x + (size_t)nload * 128 + kb * 32 + kq * 8);
    const int colbase = (kb * 32 + kq * 8) ^ ((arow & 7) << 3);
#pragma unroll
    for (int t = 0; t < 8; ++t) {
      const half8_t b = *(const half8_t*)&wt[(t * 16 + arow) * 128 + colbase];
      acc[t] = __builtin_amdgcn_mfma_f32_16x16x32_f16(a, b, acc[t], 0, 0, 0);
    }
  }
  // lane arow, tile t -> channel arow*8+t; bias is 8 contiguous floats
  const float4 bv0 = *(const float4*)&bias128[arow * 8];
  const float4 bv1 = *(const float4*)&bias128[arow * 8 + 4];
  const float bv[8] = {bv0.x, bv0.y, bv0.z, bv0.w, bv1.x, bv1.y, bv1.z, bv1.w};
#pragma unroll
  for (int i = 0; i < 4; ++i) {
    const int n = nbase + kq * 4 + i;
    if (n < NN) {
      half8_t v;
#pragma unroll
      for (int t = 0; t < 8; ++t) v[t] = (_Float16)(acc[t][i] + bv[t]);
      *(half8_t*)(out + (size_t)n * 128 + arow * 8) = v;
    }
  }
}

// ---- build: in-edge CSR (src,eidx int2) + fp16 edge-attr copy ----
__global__ void build_k(const int* __restrict__ src, const int* __restrict__ dst,
                        const float* __restrict__ eattr,
                        int* __restrict__ cnt, int2* __restrict__ bpair,
                        _Float16* __restrict__ eatt16) {
  const int e = blockIdx.x * blockDim.x + threadIdx.x;
  if (e >= NE) return;
  const float4* ea = (const float4*)(eattr + (size_t)e * FEAT_E);
  const float4 a0 = ea[0], a1 = ea[1], a2 = ea[2], a3 = ea[3];
  half8_t h0 = {(_Float16)a0.x, (_Float16)a0.y, (_Float16)a0.z, (_Float16)a0.w,
                (_Float16)a1.x, (_Float16)a1.y, (_Float16)a1.z, (_Float16)a1.w};
  half8_t h1 = {(_Float16)a2.x, (_Float16)a2.y, (_Float16)a2.z, (_Float16)a2.w,
                (_Float16)a3.x, (_Float16)a3.y, (_Float16)a3.z, (_Float16)a3.w};
  half8_t* eo = (half8_t*)(eatt16 + (size_t)e * FEAT_E);
  eo[0] = h0; eo[1] = h1;
  const int d = dst[e];
  const int pos = atomicAdd(&cnt[d], 1);
  if (pos < CAP) bpair[(size_t)d * CAP + pos] = make_int2(src[e], e);
}

// ---- FUSED per-node GATv2: persistent waves + dynamic work queue (R8) ----
// R7 post-mortem: static ~10-nodes/wave partition -> load-imbalance tail
// (occupancy 28->18.7%, dur 105->110). R8 keeps persistence (no dispatch
// limit) but restores dynamic balancing: 8 padded per-partition counters
// (partition = blockIdx&7, 6250 nodes each, ~8K atomics/counter). Per-node
// pipeline (each stage has a full node of slack):
//   iter k: [edge-loads A] [cnt for C] [atomic grab D] [bpair/xr for B]
//           [edge loop A] [store A] ; advance A<-B<-C<-D.
// Positions are monotone per counter, so once A is invalid all later are;
// break happens before any store of an invalid node.
__global__ __launch_bounds__(256) void node_gat_fused_k(
    const _Float16* __restrict__ xl16, const _Float16* __restrict__ xr16,
    const _Float16* __restrict__ eatt16,
    const int2* __restrict__ bpair, const int* __restrict__ cnt,
    const float* __restrict__ We, const float* __restrict__ att,
    const float* __restrict__ bias, _Float16* __restrict__ hout,
    int* __restrict__ qctr) {
  __shared__ half8_t WeS[FEAT_E][16];  // WeS[f][q] = We[f][8q..8q+7], 4 KB
  const int tid = threadIdx.x;
  {
    const int f = tid >> 4, q = tid & 15;
    const float4 w0 = ((const float4*)We)[f * 32 + q * 2];
    const float4 w1 = ((const float4*)We)[f * 32 + q * 2 + 1];
    WeS[f][q] = (half8_t){(_Float16)w0.x, (_Float16)w0.y, (_Float16)w0.z, (_Float16)w0.w,
                          (_Float16)w1.x, (_Float16)w1.y, (_Float16)w1.z, (_Float16)w1.w};
  }
  __syncthreads();

  const int lane = tid & 63;
  const int slot = lane >> 4, l16 = lane & 15;
  const int part = blockIdx.x & (NQPART - 1);
  const int nbase = part * NPART;
  int* ctr = qctr + part * QSTRIDE;

  const float4 af0 = ((const float4*)att)[l16 * 2];
  const float4 af1 = ((const float4*)att)[l16 * 2 + 1];
  const half2_t at01 = {(_Float16)af0.x, (_Float16)af0.y};
  const half2_t at23 = {(_Float16)af0.z, (_Float16)af0.w};
  const half2_t at45 = {(_Float16)af1.x, (_Float16)af1.y};
  const half2_t at67 = {(_Float16)af1.z, (_Float16)af1.w};
  const float4 bi0 = ((const float4*)bias)[l16 * 2];
  const float4 bi1 = ((const float4*)bias)[l16 * 2 + 1];

  // ---- queue prologue (once per wave; wave-uniform values in VGPRs) ----
  int pA = 0, pB = 0, pC = 0;
  if (lane == 0) {
    pA = atomicAdd(ctr, 1);
    pB = atomicAdd(ctr, 1);
    pC = atomicAdd(ctr, 1);
  }
  pA = __shfl(pA, 0); pB = __shfl(pB, 0); pC = __shfl(pC, 0);

  int dA = nbase + (pA < NPART ? pA : 0);
  int degA = 0;
  if (pA < NPART) {
    degA = cnt[dA];
    degA = degA < CAP ? degA : CAP;
  }
  int degB_raw = (pB < NPART) ? cnt[nbase + pB] : 0;
  int2 mypA = make_int2(0, 0);
  if (lane < degA) mypA = bpair[(size_t)dA * CAP + lane];
  half8_t xrhA = *(const half8_t*)(xr16 + (size_t)dA * HIDD + l16 * 8);

#define FINISH_EDGE(XL, EM, VALID)                                       \
  {                                                                      \
    half8_t m_ = ((XL) + xrh) + (EM);                                    \
    half8_t lk_ = hmax8(m_, m_ * splat8((_Float16)0.2f));                \
    float p_ = dot_att(lk_, at01, at23, at45, at67);                     \
    p_ += __shfl_xor(p_, 1);                                             \
    p_ += __shfl_xor(p_, 2);                                             \
    const float w_ = (VALID) ? __expf(p_) : 0.f;                         \
    den += w_;                                                           \
    acc0 = fmaf(w_, (float)(XL)[0], acc0);                               \
    acc1 = fmaf(w_, (float)(XL)[1], acc1);                               \
    acc2 = fmaf(w_, (float)(XL)[2], acc2);                               \
    acc3 = fmaf(w_, (float)(XL)[3], acc3);                               \
    acc4 = fmaf(w_, (float)(XL)[4], acc4);                               \
    acc5 = fmaf(w_, (float)(XL)[5], acc5);                               \
    acc6 = fmaf(w_, (float)(XL)[6], acc6);                               \
    acc7 = fmaf(w_, (float)(XL)[7], acc7);                               \
  }

#define LOAD_PAIR_AT(E0, E1, X0, X1, A0, B0, A1, B1)                     \
  {                                                                      \
    const int s0_ = __shfl(myp.x, (E0)), i0_ = __shfl(myp.y, (E0));      \
    const int s1_ = __shfl(myp.x, (E1)), i1_ = __shfl(myp.y, (E1));      \
    X0 = *(const half8_t*)(xl16 + (unsigned)s0_ * 128u + l16 * 8);       \
    X1 = *(const half8_t*)(xl16 + (unsigned)s1_ * 128u + l16 * 8);       \
    A0 = *(const half8_t*)(eatt16 + (unsigned)i0_ * 16u);                \
    B0 = *(const half8_t*)(eatt16 + (unsigned)i0_ * 16u + 8u);           \
    A1 = *(const half8_t*)(eatt16 + (unsigned)i1_ * 16u);                \
    B1 = *(const half8_t*)(eatt16 + (unsigned)i1_ * 16u + 8u);           \
  }

#define COMPUTE_PAIR()                                                   \
  {                                                                      \
    half8_t em0 = {}, em1 = {};                                          \
    _Pragma("unroll") for (int f = 0; f < 8; ++f) {                      \
      const half8_t wf = WeS[f][l16];                                    \
      em0 += splat8(a0[f]) * wf;                                         \
      em1 += splat8(a1[f]) * wf;                                         \
    }                                                                    \
    _Pragma("unroll") for (int f = 0; f < 8; ++f) {                      \
      const half8_t wf = WeS[8 + f][l16];                                \
      em0 += splat8(b0[f]) * wf;                                         \
      em1 += splat8(b1[f]) * wf;                                         \
    }                                                                    \
    FINISH_EDGE(x0, em0, e0 < deg)                                       \
    FINISH_EDGE(x1, em1, e1 < deg)                                       \
  }

  while (pA < NPART) {
    // ---- process node dA (state: degA, mypA, xrhA arrived) ----
    const int deg = degA;
    const int2 myp = mypA;
    const half8_t xrh = xrhA;
    float acc0 = 0.f, acc1 = 0.f, acc2 = 0.f, acc3 = 0.f;
    float acc4 = 0.f, acc5 = 0.f, acc6 = 0.f, acc7 = 0.f;
    float den = 0.f;

    const int T = (deg + 7) >> 3;
    int e0 = slot, e1 = slot + 4;
    half8_t x0, x1, a0, b0, a1, b1;
    if (T > 0) {
      LOAD_PAIR_AT(e0, e1, x0, x1, a0, b0, a1, b1)  // critical path first
    }
    // ---- pipeline issues (independent of this node's compute) ----
    const int degC_raw = cnt[nbase + (pC < NPART ? pC : 0)];  // cnt for C
    int pD = 0;
    if (lane == 0) pD = atomicAdd(ctr, 1);                    // grab D
    pD = __shfl(pD, 0);
    const bool bOK = (pB < NPART);
    const int dB = nbase + (bOK ? pB : 0);
    int degB = degB_raw < CAP ? degB_raw : CAP;
    if (!bOK) degB = 0;
    int2 mypB = make_int2(0, 0);
    if (lane < degB) mypB = bpair[(size_t)dB * CAP + lane];   // B prefetch
    half8_t xrhB = *(const half8_t*)(xr16 + (size_t)dB * HIDD + l16 * 8);

    // ---- edge loop (1-iter-ahead pipelined) ----
    if (T > 0) {
      for (int k = 0; k + 1 < T; ++k) {
        half8_t nx0, nx1, na0, nb0, na1, nb1;
        LOAD_PAIR_AT(e0 + 8, e1 + 8, nx0, nx1, na0, nb0, na1, nb1)
        COMPUTE_PAIR()
        e0 += 8; e1 += 8;
        x0 = nx0; x1 = nx1; a0 = na0; b0 = nb0; a1 = na1; b1 = nb1;
      }
      const bool pairLast = (((T - 1) << 3) + 4) < deg;
      if (pairLast) {
        COMPUTE_PAIR()
      } else {
        half8_t em0 = {};
#pragma unroll
        for (int f = 0; f < 8; ++f) em0 += splat8(a0[f]) * WeS[f][l16];
#pragma unroll
        for (int f = 0; f < 8; ++f) em0 += splat8(b0[f]) * WeS[8 + f][l16];
        FINISH_EDGE(x0, em0, e0 < deg)
      }
    }

    // ---- combine 4 slots, ELU + bias, store ----
#define RED(A) A += __shfl_xor(A, 16); A += __shfl_xor(A, 32);
    RED(acc0) RED(acc1) RED(acc2) RED(acc3)
    RED(acc4) RED(acc5) RED(acc6) RED(acc7)
    RED(den)
#undef RED
    if (slot == 0) {
      const float inv = 1.f / (den + 1e-16f);
      float o0 = fmaf(acc0, inv, bi0.x), o1 = fmaf(acc1, inv, bi0.y);
      float o2 = fmaf(acc2, inv, bi0.z), o3 = fmaf(acc3, inv, bi0.w);
      float o4 = fmaf(acc4, inv, bi1.x), o5 = fmaf(acc5, inv, bi1.y);
      float o6 = fmaf(acc6, inv, bi1.z), o7 = fmaf(acc7, inv, bi1.w);
      o0 = o0 > 0.f ? o0 : expm1f(o0);  o1 = o1 > 0.f ? o1 : expm1f(o1);
      o2 = o2 > 0.f ? o2 : expm1f(o2);  o3 = o3 > 0.f ? o3 : expm1f(o3);
      o4 = o4 > 0.f ? o4 : expm1f(o4);  o5 = o5 > 0.f ? o5 : expm1f(o5);
      o6 = o6 > 0.f ? o6 : expm1f(o6);  o7 = o7 > 0.f ? o7 : expm1f(o7);
      half8_t ho = {(_Float16)o0, (_Float16)o1, (_Float16)o2, (_Float16)o3,
                    (_Float16)o4, (_Float16)o5, (_Float16)o6, (_Float16)o7};
      *(half8_t*)(hout + (size_t)dA * HIDD + l16 * 8) = ho;
    }

    // ---- advance pipeline: A<-B, B<-C, C<-D ----
    pA = pB; dA = dB; degA = degB; mypA = mypB; xrhA = xrhB;
    pB = pC; degB_raw = degC_raw;
    pC = pD;
  }
#undef COMPUTE_PAIR
#undef LOAD_PAIR_AT
#undef FINISH_EDGE
}

// ---- graph pooling (fp16 h, standard layout) ----
__global__ void pool_k(const _Float16* __restrict__ h, const int* __restrict__ batch,
                       float* __restrict__ gsum, unsigned int* __restrict__ gmax,
                       float* __restrict__ gcnt) {
  __shared__ float ssum[NGRAPH][HIDD];
  __shared__ float smax[NGRAPH][HIDD];
  __shared__ float scnt[NGRAPH];
  const int t = threadIdx.x;
#pragma unroll
  for (int g = 0; g < NGRAPH; ++g) {
    ssum[g][t] = 0.f;
    smax[g][t] = -3.0e38f;
  }
  if (t < NGRAPH) scnt[t] = 0.f;
  __syncthreads();
  const int n0 = blockIdx.x * 64;
  const int nEnd = (n0 + 64 < NN) ? (n0 + 64) : NN;
  unsigned int seen = 0;
  for (int n = n0; n < nEnd; ++n) {
    const int g = batch[n];
    seen |= 1u << g;
    const float v = (float)h[(size_t)n * HIDD + t];
    ssum[g][t] += v;
    smax[g][t] = fmaxf(smax[g][t], v);
    if (t == 0) scnt[g] += 1.f;
  }
  __syncthreads();
  for (int g = 0; g < NGRAPH; ++g) {
    if (seen & (1u << g)) {
      atomicAdd(&gsum[g * HIDD + t], ssum[g][t]);
      atomicMax(&gmax[g * HIDD + t], fenc(smax[g][t]));
      if (t == 0) atomicAdd(&gcnt[g], scnt[g]);
    }
  }
}

// ---- FC head ----
__global__ void head_k(const float* __restrict__ suma, const unsigned int* __restrict__ maxa,
                       const float* __restrict__ cnta,
                       const float* __restrict__ sumb, const unsigned int* __restrict__ maxb,
                       const float* __restrict__ cntb,
                       const float* __restrict__ Wf1, const float* __restrict__ bf1,
                       const float* __restrict__ Wf2, const float* __restrict__ bf2,
                       float* __restrict__ out) {
  __shared__ float c[4 * HIDD];
  __shared__ float red[HIDD];
  const int g = blockIdx.x, t = threadIdx.x;  // 128 threads
  const float ca = fmaxf(cnta[g], 1.f), cb = fmaxf(cntb[g], 1.f);
  c[t]            = suma[g * HIDD + t] / ca;
  c[HIDD + t]     = fdec(maxa[g * HIDD + t]);
  c[2 * HIDD + t] = sumb[g * HIDD + t] / cb;
  c[3 * HIDD + t] = fdec(maxb[g * HIDD + t]);
  __syncthreads();
  float acc = bf1[t];
  for (int i = 0; i < 4 * HIDD; ++i)
    acc = fmaf(c[i], Wf1[(size_t)i * HIDD + t], acc);
  acc = fmaxf(acc, 0.f);
  red[t] = acc * Wf2[t];
  __syncthreads();
  for (int s2 = 64; s2 > 0; s2 >>= 1) {
    if (t < s2) red[t] += red[t + s2];
    __syncthreads();
  }
  if (t == 0) out[g] = 1.f / (1.f + expf(-(red[0] + bf2[0])));
}

extern "C" void kernel_launch(void* const* d_in, const int* in_sizes, int n_in,
                              void* d_out, int out_size, void* d_ws, size_t ws_size,
                              hipStream_t stream) {
  (void)in_sizes; (void)n_in; (void)out_size; (void)ws_size;
  const float* xA    = (const float*)d_in[0];
  const int*   eiA   = (const int*)  d_in[1];
  const float* eaA   = (const float*)d_in[2];
  const int*   batA  = (const int*)  d_in[3];
  const float* xB    = (const float*)d_in[4];
  const int*   eiB   = (const int*)  d_in[5];
  const float* eaB   = (const float*)d_in[6];
  const int*   batB  = (const int*)  d_in[7];
  const float* W1l   = (const float*)d_in[8];
  const float* b1l   = (const float*)d_in[9];
  const float* W1r   = (const float*)d_in[10];
  const float* b1r   = (const float*)d_in[11];
  const float* W1e   = (const float*)d_in[12];
  const float* att1  = (const float*)d_in[13];
  const float* bias1 = (const float*)d_in[14];
  const float* W2l   = (const float*)d_in[15];
  const float* b2l   = (const float*)d_in[16];
  const float* W2r   = (const float*)d_in[17];
  const float* b2r   = (const float*)d_in[18];
  const float* W2e   = (const float*)d_in[19];
  const float* att2  = (const float*)d_in[20];
  const float* bias2 = (const float*)d_in[21];
  const float* Wf1   = (const float*)d_in[22];
  const float* bf1   = (const float*)d_in[23];
  const float* Wf2   = (const float*)d_in[24];
  const float* bf2   = (const float*)d_in[25];

  char* ws = (char*)d_ws;
  size_t off = 0;
  auto alloc = [&](size_t bytes) -> void* {
    void* p = ws + off;
    off += (bytes + 255) & ~(size_t)255;
    return p;
  };
  _Float16* h16    = (_Float16*)alloc((size_t)NN * HIDD * 2);
  _Float16* xl16   = (_Float16*)alloc((size_t)NN * HIDD * 2);
  _Float16* xr16   = (_Float16*)alloc((size_t)NN * HIDD * 2);
  int2*     bpair  = (int2*)    alloc((size_t)NN * CAP * 8);
  _Float16* eatt16 = (_Float16*)alloc((size_t)NE * FEAT_E * 2);
  int*      cnt    = (int*)     alloc((size_t)NN * 4);
  _Float16* wtg1   = (_Float16*)alloc(2 * 128 * 128 * 2);
  _Float16* wtg2   = (_Float16*)alloc(2 * 128 * 128 * 2);
  int*      qctr   = (int*)     alloc(4 * NQPART * QSTRIDE * 4);  // 4 launches
  const size_t poolStart = off;
  float*        psumA = (float*)alloc(NGRAPH * HIDD * 4);
  unsigned int* pmaxA = (unsigned int*)alloc(NGRAPH * HIDD * 4);
  float*        pcntA = (float*)alloc(NGRAPH * 4);
  float*        psumB = (float*)alloc(NGRAPH * HIDD * 4);
  unsigned int* pmaxB = (unsigned int*)alloc(NGRAPH * HIDD * 4);
  float*        pcntB = (float*)alloc(NGRAPH * 4);
  const size_t poolBytes = off - poolStart;

  const float* xs[2]   = {xA, xB};
  const int*   eis[2]  = {eiA, eiB};
  const float* eas[2]  = {eaA, eaB};
  const int*   bats[2] = {batA, batB};
  float*        psums[2] = {psumA, psumB};
  unsigned int* pmaxs[2] = {pmaxA, pmaxB};
  float*        pcnts[2] = {pcntA, pcntB};

  hipMemsetAsync(psumA, 0, poolBytes, stream);  // 0 == encoded -inf for max
  hipMemsetAsync(qctr, 0, 4 * NQPART * QSTRIDE * 4, stream);
  prep_wt_k<<<256, 128, 0, stream>>>(W1l, W1r, wtg1);
  prep_wt_k<<<256, 128, 0, stream>>>(W2l, W2r, wtg2);

  int launchIdx = 0;
  for (int g = 0; g < 2; ++g) {
    const int* src = eis[g];
    const int* dst = eis[g] + NE;
    hipMemsetAsync(cnt, 0, (size_t)NN * 4, stream);
    build_k<<<NE / 256, 256, 0, stream>>>(src, dst, eas[g], cnt, bpair, eatt16);
    // layer 1 (fp32 x input)
    node_linear_mfma_k<float><<<dim3((NN + 63) / 64, 2), 256, 0, stream>>>(
        xs[g], wtg1, b1l, b1r, xl16, xr16);
    node_gat_fused_k<<<GATBLK, 256, 0, stream>>>(
        xl16, xr16, eatt16, bpair, cnt, W1e, att1, bias1, h16,
        qctr + (launchIdx++) * NQPART * QSTRIDE);
    // layer 2 (fp16 h input, standard layout)
    node_linear_mfma_k<_Float16><<<dim3((NN + 63) / 64, 2), 256, 0, stream>>>(
        h16, wtg2, b2l, b2r, xl16, xr16);
    node_gat_fused_k<<<GATBLK, 256, 0, stream>>>(
        xl16, xr16, eatt16, bpair, cnt, W2e, att2, bias2, h16,
        qctr + (launchIdx++) * NQPART * QSTRIDE);
    // pooling
    pool_k<<<(NN + 63) / 64, 128, 0, stream>>>(h16, bats[g], psums[g], pmaxs[g], pcnts[g]);
  }
  head_k<<<NGRAPH, 128, 0, stream>>>(psumA, pmaxA, pcntA, psumB, pmaxB, pcntB,
                                     Wf1, bf1, Wf2, bf2, (float*)d_out);
}

// Round 7
// 832.322 us; speedup vs baseline: 1.1606x; 1.1606x over previous
//
#include <hip/hip_runtime.h>
#include <hip/hip_fp16.h>

#define NN 50000
#define NE 800000
#define HIDD 128
#define FEAT_E 16
#define NGRAPH 8
#define CAP 64

typedef __attribute__((ext_vector_type(2))) _Float16 half2_t;
typedef __attribute__((ext_vector_type(8))) _Float16 half8_t;
typedef __attribute__((ext_vector_type(4))) float floatx4;

// Layout note: node_linear's MFMA epilogue computes, for tile t and lane
// arow, output channel oc(t,arow) = arow*8 + t (set by column-ordering the
// staged weight matrix wtg). Lane arow therefore holds channels
// [arow*8, arow*8+8) contiguously -> ONE half8 store in STANDARD layout,
// and the fused kernel's lane l16 owns 8 contiguous same-head channels
// (head = l16>>2). No permutation anywhere else in the pipeline.

// ---- order-preserving float<->uint encoding for atomicMax on floats ----
__device__ __forceinline__ unsigned int fenc(float f) {
  unsigned int u = __float_as_uint(f);
  return (u & 0x80000000u) ? ~u : (u | 0x80000000u);
}
__device__ __forceinline__ float fdec(unsigned int u) {
  if (u == 0u) return 0.0f;
  float f = (u & 0x80000000u) ? __uint_as_float(u & 0x7fffffffu)
                              : __uint_as_float(~u);
  return __builtin_isfinite(f) ? f : 0.0f;
}

__device__ __forceinline__ half8_t splat8(_Float16 v) {
  return (half8_t){v, v, v, v, v, v, v, v};
}
__device__ __forceinline__ half8_t hmax8(half8_t a, half8_t b) {
#if __has_builtin(__builtin_elementwise_max)
  return __builtin_elementwise_max(a, b);
#else
  half8_t r;
#pragma unroll
  for (int i = 0; i < 8; ++i) r[i] = a[i] > b[i] ? a[i] : b[i];
  return r;
#endif
}
__device__ __forceinline__ float dot_att(half8_t lk, half2_t t01, half2_t t23,
                                         half2_t t45, half2_t t67) {
#if __has_builtin(__builtin_amdgcn_fdot2)
  float p = __builtin_amdgcn_fdot2((half2_t){lk[0], lk[1]}, t01, 0.f, false);
  p = __builtin_amdgcn_fdot2((half2_t){lk[2], lk[3]}, t23, p, false);
  p = __builtin_amdgcn_fdot2((half2_t){lk[4], lk[5]}, t45, p, false);
  p = __builtin_amdgcn_fdot2((half2_t){lk[6], lk[7]}, t67, p, false);
  return p;
#else
  float p = 0.f;
  p += (float)lk[0] * (float)t01[0] + (float)lk[1] * (float)t01[1];
  p += (float)lk[2] * (float)t23[0] + (float)lk[3] * (float)t23[1];
  p += (float)lk[4] * (float)t45[0] + (float)lk[5] * (float)t45[1];
  p += (float)lk[6] * (float)t67[0] + (float)lk[7] * (float)t67[1];
  return p;
#endif
}

// ---- prep: wtg[which(2)][r(128)][col(128)] fp16, col = k ^ ((r&7)<<3).
// Row r of the staged matrix holds W[:, oc_src(r)] with
// oc_src(r) = (r&15)*8 + (r>>4)  -> identity output layout (see note above).
__global__ void prep_wt_k(const float* __restrict__ Wl, const float* __restrict__ Wr,
                          _Float16* __restrict__ wtg) {
  const int r = blockIdx.x & 127;
  const int which = blockIdx.x >> 7;
  const int k = threadIdx.x;  // 0..127
  const float* W = which ? Wr : Wl;
  const int oc_src = (r & 15) * 8 + (r >> 4);
  const int col = k ^ ((r & 7) << 3);
  wtg[(which * 128 + r) * 128 + col] = (_Float16)W[k * 128 + oc_src];
}

// ---- A-fragment loaders (fp32 input layer 1, fp16 layer 2) ----
__device__ __forceinline__ half8_t load_a8(const _Float16* p) {
  return *(const half8_t*)p;
}
__device__ __forceinline__ half8_t load_a8(const float* p) {
  const float4 f0 = *(const float4*)p;
  const float4 f1 = *(const float4*)(p + 4);
  return (half8_t){(_Float16)f0.x, (_Float16)f0.y, (_Float16)f0.z, (_Float16)f0.w,
                   (_Float16)f1.x, (_Float16)f1.y, (_Float16)f1.z, (_Float16)f1.w};
}

// ---- node linear via MFMA, LDS-staged swizzled weights ----
// grid (ceil(NN/64), 2): blockIdx.y = 0 -> xl (Wl), 1 -> xr (Wr).
// block 256 = 4 waves; wave = 16 nodes x 128 outs (8 tiles, 32 acc VGPR).
// Epilogue: lane arow stores channels [arow*8, arow*8+8) as one half8.
template <typename TIN>
__global__ __launch_bounds__(256) void node_linear_mfma_k(
    const TIN* __restrict__ x, const _Float16* __restrict__ wtg,
    const float* __restrict__ bl, const float* __restrict__ br,
    _Float16* __restrict__ xl16, _Float16* __restrict__ xr16) {
  __shared__ _Float16 wt[128 * 128];  // 32 KB
  const int tid = threadIdx.x;
  const int which = blockIdx.y;
  const _Float16* wsrc = wtg + which * (128 * 128);
  const float* bias128 = which ? br : bl;
  _Float16* out = which ? xr16 : xl16;
  {
    const half8_t* src = (const half8_t*)wsrc;
    half8_t* dstl = (half8_t*)wt;
#pragma unroll
    for (int it = 0; it < 8; ++it)
      dstl[it * 256 + tid] = src[it * 256 + tid];
  }
  __syncthreads();

  const int wv = tid >> 6, lane = tid & 63;
  const int arow = lane & 15, kq = lane >> 4;
  const int nbase = blockIdx.x * 64 + wv * 16;
  int nload = nbase + arow;
  if (nload >= NN) nload = NN - 1;
  floatx4 acc[8];
#pragma unroll
  for (int t = 0; t < 8; ++t) acc[t] = (floatx4){0.f, 0.f, 0.f, 0.f};
#pragma unroll
  for (int kb = 0; kb < 4; ++kb) {
    const half8_t a = load_a8(x + (size_t)nload * 128 + kb * 32 + kq * 8);
    const int colbase = (kb * 32 + kq * 8) ^ ((arow & 7) << 3);
#pragma unroll
    for (int t = 0; t < 8; ++t) {
      const half8_t b = *(const half8_t*)&wt[(t * 16 + arow) * 128 + colbase];
      acc[t] = __builtin_amdgcn_mfma_f32_16x16x32_f16(a, b, acc[t], 0, 0, 0);
    }
  }
  // lane arow, tile t -> channel arow*8+t; bias is 8 contiguous floats
  const float4 bv0 = *(const float4*)&bias128[arow * 8];
  const float4 bv1 = *(const float4*)&bias128[arow * 8 + 4];
  const float bv[8] = {bv0.x, bv0.y, bv0.z, bv0.w, bv1.x, bv1.y, bv1.z, bv1.w};
#pragma unroll
  for (int i = 0; i < 4; ++i) {
    const int n = nbase + kq * 4 + i;
    if (n < NN) {
      half8_t v;
#pragma unroll
      for (int t = 0; t < 8; ++t) v[t] = (_Float16)(acc[t][i] + bv[t]);
      *(half8_t*)(out + (size_t)n * 128 + arow * 8) = v;
    }
  }
}

// ---- build: in-edge CSR (src,eidx int2) + fp16 edge-attr copy ----
__global__ void build_k(const int* __restrict__ src, const int* __restrict__ dst,
                        const float* __restrict__ eattr,
                        int* __restrict__ cnt, int2* __restrict__ bpair,
                        _Float16* __restrict__ eatt16) {
  const int e = blockIdx.x * blockDim.x + threadIdx.x;
  if (e >= NE) return;
  const float4* ea = (const float4*)(eattr + (size_t)e * FEAT_E);
  const float4 a0 = ea[0], a1 = ea[1], a2 = ea[2], a3 = ea[3];
  half8_t h0 = {(_Float16)a0.x, (_Float16)a0.y, (_Float16)a0.z, (_Float16)a0.w,
                (_Float16)a1.x, (_Float16)a1.y, (_Float16)a1.z, (_Float16)a1.w};
  half8_t h1 = {(_Float16)a2.x, (_Float16)a2.y, (_Float16)a2.z, (_Float16)a2.w,
                (_Float16)a3.x, (_Float16)a3.y, (_Float16)a3.z, (_Float16)a3.w};
  half8_t* eo = (half8_t*)(eatt16 + (size_t)e * FEAT_E);
  eo[0] = h0; eo[1] = h1;
  const int d = dst[e];
  const int pos = atomicAdd(&cnt[d], 1);
  if (pos < CAP) bpair[(size_t)d * CAP + pos] = make_int2(src[e], e);
}

// ---- FUSED per-node GATv2 (R9): 2 nodes/wave + parallel prologue ----
// Evidence trail: R6 (1 node/wave, 12500 blocks) = 105us at 119 blocks/us
// = 8.4ns/block -> consistent with CP dispatch-rate limit. R7 (10 nodes/
// wave static) and R8 (dynamic queue) both regressed -> overshot into
// tail/serialization. R9 interpolates: grid = NN/8 = 6250 blocks, each
// wave processes d0 in [0,25000) and d1 = d0+25000 sequentially.
// Second fix: bpair rows are loaded UNCONDITIONALLY (lane<CAP always
// in-allocation) with index clamping after arrival, so the per-node
// prologue chain cnt->bpair->gather becomes cnt || bpair || xr (6
// independent loads for both nodes at wave start). Node 1's prologue
// fully hides under node 0's edge loop. Invalid lanes contribute w_=0
// exactly as in R6 (bit-identical accumulation).
__global__ __launch_bounds__(256) void node_gat_fused_k(
    const _Float16* __restrict__ xl16, const _Float16* __restrict__ xr16,
    const _Float16* __restrict__ eatt16,
    const int2* __restrict__ bpair, const int* __restrict__ cnt,
    const float* __restrict__ We, const float* __restrict__ att,
    const float* __restrict__ bias, _Float16* __restrict__ hout) {
  __shared__ half8_t WeS[FEAT_E][16];  // WeS[f][q] = We[f][8q..8q+7], 4 KB
  const int tid = threadIdx.x;
  {
    const int f = tid >> 4, q = tid & 15;
    const float4 w0 = ((const float4*)We)[f * 32 + q * 2];
    const float4 w1 = ((const float4*)We)[f * 32 + q * 2 + 1];
    WeS[f][q] = (half8_t){(_Float16)w0.x, (_Float16)w0.y, (_Float16)w0.z, (_Float16)w0.w,
                          (_Float16)w1.x, (_Float16)w1.y, (_Float16)w1.z, (_Float16)w1.w};
  }
  __syncthreads();

  const int wave = tid >> 6, lane = tid & 63;
  const int slot = lane >> 4, l16 = lane & 15;
  const int d0 = blockIdx.x * 4 + wave;  // [0, 25000)
  const int d1 = d0 + NN / 2;            // [25000, 50000)

  const float4 af0 = ((const float4*)att)[l16 * 2];
  const float4 af1 = ((const float4*)att)[l16 * 2 + 1];
  const half2_t at01 = {(_Float16)af0.x, (_Float16)af0.y};
  const half2_t at23 = {(_Float16)af0.z, (_Float16)af0.w};
  const half2_t at45 = {(_Float16)af1.x, (_Float16)af1.y};
  const half2_t at67 = {(_Float16)af1.z, (_Float16)af1.w};
  const float4 bi0 = ((const float4*)bias)[l16 * 2];
  const float4 bi1 = ((const float4*)bias)[l16 * 2 + 1];

  // ---- parallel prologue: 6 independent loads for BOTH nodes ----
  int degA = cnt[d0];
  int degB = cnt[d1];
  int2 mypA = bpair[(size_t)d0 * CAP + lane];  // unconditional (lane<CAP)
  int2 mypB = bpair[(size_t)d1 * CAP + lane];
  const half8_t xrhA = *(const half8_t*)(xr16 + (size_t)d0 * HIDD + l16 * 8);
  const half8_t xrhB = *(const half8_t*)(xr16 + (size_t)d1 * HIDD + l16 * 8);
  degA = degA < CAP ? degA : CAP;
  degB = degB < CAP ? degB : CAP;
  // clamp stale/garbage entries (lanes >= deg) to safe in-bounds indices;
  // their contributions are masked to exactly 0 in FINISH_EDGE.
  mypA.x = ((unsigned)mypA.x < NN) ? mypA.x : 0;
  mypA.y = ((unsigned)mypA.y < NE) ? mypA.y : 0;
  mypB.x = ((unsigned)mypB.x < NN) ? mypB.x : 0;
  mypB.y = ((unsigned)mypB.y < NE) ? mypB.y : 0;

#define FINISH_EDGE(XL, EM, VALID)                                       \
  {                                                                      \
    half8_t m_ = ((XL) + xrh) + (EM);                                    \
    half8_t lk_ = hmax8(m_, m_ * splat8((_Float16)0.2f));                \
    float p_ = dot_att(lk_, at01, at23, at45, at67);                     \
    p_ += __shfl_xor(p_, 1);                                             \
    p_ += __shfl_xor(p_, 2);                                             \
    const float w_ = (VALID) ? __expf(p_) : 0.f;                         \
    den += w_;                                                           \
    acc0 = fmaf(w_, (float)(XL)[0], acc0);                               \
    acc1 = fmaf(w_, (float)(XL)[1], acc1);                               \
    acc2 = fmaf(w_, (float)(XL)[2], acc2);                               \
    acc3 = fmaf(w_, (float)(XL)[3], acc3);                               \
    acc4 = fmaf(w_, (float)(XL)[4], acc4);                               \
    acc5 = fmaf(w_, (float)(XL)[5], acc5);                               \
    acc6 = fmaf(w_, (float)(XL)[6], acc6);                               \
    acc7 = fmaf(w_, (float)(XL)[7], acc7);                               \
  }

#define LOAD_PAIR_AT(E0, E1, X0, X1, A0, B0, A1, B1)                     \
  {                                                                      \
    const int s0_ = __shfl(myp.x, (E0)), i0_ = __shfl(myp.y, (E0));      \
    const int s1_ = __shfl(myp.x, (E1)), i1_ = __shfl(myp.y, (E1));      \
    X0 = *(const half8_t*)(xl16 + (unsigned)s0_ * 128u + l16 * 8);       \
    X1 = *(const half8_t*)(xl16 + (unsigned)s1_ * 128u + l16 * 8);       \
    A0 = *(const half8_t*)(eatt16 + (unsigned)i0_ * 16u);                \
    B0 = *(const half8_t*)(eatt16 + (unsigned)i0_ * 16u + 8u);           \
    A1 = *(const half8_t*)(eatt16 + (unsigned)i1_ * 16u);                \
    B1 = *(const half8_t*)(eatt16 + (unsigned)i1_ * 16u + 8u);           \
  }

#define COMPUTE_PAIR()                                                   \
  {                                                                      \
    half8_t em0 = {}, em1 = {};                                          \
    _Pragma("unroll") for (int f = 0; f < 8; ++f) {                      \
      const half8_t wf = WeS[f][l16];                                    \
      em0 += splat8(a0[f]) * wf;                                         \
      em1 += splat8(a1[f]) * wf;                                         \
    }                                                                    \
    _Pragma("unroll") for (int f = 0; f < 8; ++f) {                      \
      const half8_t wf = WeS[8 + f][l16];                                \
      em0 += splat8(b0[f]) * wf;                                         \
      em1 += splat8(b1[f]) * wf;                                         \
    }                                                                    \
    FINISH_EDGE(x0, em0, e0 < deg)                                       \
    FINISH_EDGE(x1, em1, e1 < deg)                                       \
  }

// Full per-node pipeline: edge loop (1-iter-ahead), slot reduce, store.
#define PROCESS_NODE(DN, DEG, MYP, XRH)                                  \
  {                                                                      \
    const int deg = (DEG);                                               \
    const int2 myp = (MYP);                                              \
    const half8_t xrh = (XRH);                                           \
    float acc0 = 0.f, acc1 = 0.f, acc2 = 0.f, acc3 = 0.f;                \
    float acc4 = 0.f, acc5 = 0.f, acc6 = 0.f, acc7 = 0.f;                \
    float den = 0.f;                                                     \
    const int T = (deg + 7) >> 3;                                        \
    int e0 = slot, e1 = slot + 4;                                        \
    half8_t x0, x1, a0, b0, a1, b1;                                      \
    if (T > 0) {                                                         \
      LOAD_PAIR_AT(e0, e1, x0, x1, a0, b0, a1, b1)                       \
      for (int k = 0; k + 1 < T; ++k) {                                  \
        half8_t nx0, nx1, na0, nb0, na1, nb1;                            \
        LOAD_PAIR_AT(e0 + 8, e1 + 8, nx0, nx1, na0, nb0, na1, nb1)       \
        COMPUTE_PAIR()                                                   \
        e0 += 8; e1 += 8;                                                \
        x0 = nx0; x1 = nx1; a0 = na0; b0 = nb0; a1 = na1; b1 = nb1;      \
      }                                                                  \
      const bool pairLast = (((T - 1) << 3) + 4) < deg;                  \
      if (pairLast) {                                                    \
        COMPUTE_PAIR()                                                   \
      } else {                                                           \
        half8_t em0 = {};                                                \
        _Pragma("unroll") for (int f = 0; f < 8; ++f)                    \
            em0 += splat8(a0[f]) * WeS[f][l16];                          \
        _Pragma("unroll") for (int f = 0; f < 8; ++f)                    \
            em0 += splat8(b0[f]) * WeS[8 + f][l16];                      \
        FINISH_EDGE(x0, em0, e0 < deg)                                   \
      }                                                                  \
    }                                                                    \
    acc0 += __shfl_xor(acc0, 16); acc0 += __shfl_xor(acc0, 32);          \
    acc1 += __shfl_xor(acc1, 16); acc1 += __shfl_xor(acc1, 32);          \
    acc2 += __shfl_xor(acc2, 16); acc2 += __shfl_xor(acc2, 32);          \
    acc3 += __shfl_xor(acc3, 16); acc3 += __shfl_xor(acc3, 32);          \
    acc4 += __shfl_xor(acc4, 16); acc4 += __shfl_xor(acc4, 32);          \
    acc5 += __shfl_xor(acc5, 16); acc5 += __shfl_xor(acc5, 32);          \
    acc6 += __shfl_xor(acc6, 16); acc6 += __shfl_xor(acc6, 32);          \
    acc7 += __shfl_xor(acc7, 16); acc7 += __shfl_xor(acc7, 32);          \
    den  += __shfl_xor(den, 16);  den  += __shfl_xor(den, 32);           \
    if (slot == 0) {                                                     \
      const float inv = 1.f / (den + 1e-16f);                            \
      float o0 = fmaf(acc0, inv, bi0.x), o1 = fmaf(acc1, inv, bi0.y);    \
      float o2 = fmaf(acc2, inv, bi0.z), o3 = fmaf(acc3, inv, bi0.w);    \
      float o4 = fmaf(acc4, inv, bi1.x), o5 = fmaf(acc5, inv, bi1.y);    \
      float o6 = fmaf(acc6, inv, bi1.z), o7 = fmaf(acc7, inv, bi1.w);    \
      o0 = o0 > 0.f ? o0 : expm1f(o0);  o1 = o1 > 0.f ? o1 : expm1f(o1); \
      o2 = o2 > 0.f ? o2 : expm1f(o2);  o3 = o3 > 0.f ? o3 : expm1f(o3); \
      o4 = o4 > 0.f ? o4 : expm1f(o4);  o5 = o5 > 0.f ? o5 : expm1f(o5); \
      o6 = o6 > 0.f ? o6 : expm1f(o6);  o7 = o7 > 0.f ? o7 : expm1f(o7); \
      half8_t ho = {(_Float16)o0, (_Float16)o1, (_Float16)o2,            \
                    (_Float16)o3, (_Float16)o4, (_Float16)o5,            \
                    (_Float16)o6, (_Float16)o7};                         \
      *(half8_t*)(hout + (size_t)(DN) * HIDD + l16 * 8) = ho;            \
    }                                                                    \
  }

  PROCESS_NODE(d0, degA, mypA, xrhA)
  PROCESS_NODE(d1, degB, mypB, xrhB)

#undef PROCESS_NODE
#undef COMPUTE_PAIR
#undef LOAD_PAIR_AT
#undef FINISH_EDGE
}

// ---- graph pooling (fp16 h, standard layout) ----
__global__ void pool_k(const _Float16* __restrict__ h, const int* __restrict__ batch,
                       float* __restrict__ gsum, unsigned int* __restrict__ gmax,
                       float* __restrict__ gcnt) {
  __shared__ float ssum[NGRAPH][HIDD];
  __shared__ float smax[NGRAPH][HIDD];
  __shared__ float scnt[NGRAPH];
  const int t = threadIdx.x;
#pragma unroll
  for (int g = 0; g < NGRAPH; ++g) {
    ssum[g][t] = 0.f;
    smax[g][t] = -3.0e38f;
  }
  if (t < NGRAPH) scnt[t] = 0.f;
  __syncthreads();
  const int n0 = blockIdx.x * 64;
  const int nEnd = (n0 + 64 < NN) ? (n0 + 64) : NN;
  unsigned int seen = 0;
  for (int n = n0; n < nEnd; ++n) {
    const int g = batch[n];
    seen |= 1u << g;
    const float v = (float)h[(size_t)n * HIDD + t];
    ssum[g][t] += v;
    smax[g][t] = fmaxf(smax[g][t], v);
    if (t == 0) scnt[g] += 1.f;
  }
  __syncthreads();
  for (int g = 0; g < NGRAPH; ++g) {
    if (seen & (1u << g)) {
      atomicAdd(&gsum[g * HIDD + t], ssum[g][t]);
      atomicMax(&gmax[g * HIDD + t], fenc(smax[g][t]));
      if (t == 0) atomicAdd(&gcnt[g], scnt[g]);
    }
  }
}

// ---- FC head ----
__global__ void head_k(const float* __restrict__ suma, const unsigned int* __restrict__ maxa,
                       const float* __restrict__ cnta,
                       const float* __restrict__ sumb, const unsigned int* __restrict__ maxb,
                       const float* __restrict__ cntb,
                       const float* __restrict__ Wf1, const float* __restrict__ bf1,
                       const float* __restrict__ Wf2, const float* __restrict__ bf2,
                       float* __restrict__ out) {
  __shared__ float c[4 * HIDD];
  __shared__ float red[HIDD];
  const int g = blockIdx.x, t = threadIdx.x;  // 128 threads
  const float ca = fmaxf(cnta[g], 1.f), cb = fmaxf(cntb[g], 1.f);
  c[t]            = suma[g * HIDD + t] / ca;
  c[HIDD + t]     = fdec(maxa[g * HIDD + t]);
  c[2 * HIDD + t] = sumb[g * HIDD + t] / cb;
  c[3 * HIDD + t] = fdec(maxb[g * HIDD + t]);
  __syncthreads();
  float acc = bf1[t];
  for (int i = 0; i < 4 * HIDD; ++i)
    acc = fmaf(c[i], Wf1[(size_t)i * HIDD + t], acc);
  acc = fmaxf(acc, 0.f);
  red[t] = acc * Wf2[t];
  __syncthreads();
  for (int s2 = 64; s2 > 0; s2 >>= 1) {
    if (t < s2) red[t] += red[t + s2];
    __syncthreads();
  }
  if (t == 0) out[g] = 1.f / (1.f + expf(-(red[0] + bf2[0])));
}

extern "C" void kernel_launch(void* const* d_in, const int* in_sizes, int n_in,
                              void* d_out, int out_size, void* d_ws, size_t ws_size,
                              hipStream_t stream) {
  (void)in_sizes; (void)n_in; (void)out_size; (void)ws_size;
  const float* xA    = (const float*)d_in[0];
  const int*   eiA   = (const int*)  d_in[1];
  const float* eaA   = (const float*)d_in[2];
  const int*   batA  = (const int*)  d_in[3];
  const float* xB    = (const float*)d_in[4];
  const int*   eiB   = (const int*)  d_in[5];
  const float* eaB   = (const float*)d_in[6];
  const int*   batB  = (const int*)  d_in[7];
  const float* W1l   = (const float*)d_in[8];
  const float* b1l   = (const float*)d_in[9];
  const float* W1r   = (const float*)d_in[10];
  const float* b1r   = (const float*)d_in[11];
  const float* W1e   = (const float*)d_in[12];
  const float* att1  = (const float*)d_in[13];
  const float* bias1 = (const float*)d_in[14];
  const float* W2l   = (const float*)d_in[15];
  const float* b2l   = (const float*)d_in[16];
  const float* W2r   = (const float*)d_in[17];
  const float* b2r   = (const float*)d_in[18];
  const float* W2e   = (const float*)d_in[19];
  const float* att2  = (const float*)d_in[20];
  const float* bias2 = (const float*)d_in[21];
  const float* Wf1   = (const float*)d_in[22];
  const float* bf1   = (const float*)d_in[23];
  const float* Wf2   = (const float*)d_in[24];
  const float* bf2   = (const float*)d_in[25];

  char* ws = (char*)d_ws;
  size_t off = 0;
  auto alloc = [&](size_t bytes) -> void* {
    void* p = ws + off;
    off += (bytes + 255) & ~(size_t)255;
    return p;
  };
  _Float16* h16    = (_Float16*)alloc((size_t)NN * HIDD * 2);
  _Float16* xl16   = (_Float16*)alloc((size_t)NN * HIDD * 2);
  _Float16* xr16   = (_Float16*)alloc((size_t)NN * HIDD * 2);
  int2*     bpair  = (int2*)    alloc((size_t)NN * CAP * 8);
  _Float16* eatt16 = (_Float16*)alloc((size_t)NE * FEAT_E * 2);
  int*      cnt    = (int*)     alloc((size_t)NN * 4);
  _Float16* wtg1   = (_Float16*)alloc(2 * 128 * 128 * 2);
  _Float16* wtg2   = (_Float16*)alloc(2 * 128 * 128 * 2);
  const size_t poolStart = off;
  float*        psumA = (float*)alloc(NGRAPH * HIDD * 4);
  unsigned int* pmaxA = (unsigned int*)alloc(NGRAPH * HIDD * 4);
  float*        pcntA = (float*)alloc(NGRAPH * 4);
  float*        psumB = (float*)alloc(NGRAPH * HIDD * 4);
  unsigned int* pmaxB = (unsigned int*)alloc(NGRAPH * HIDD * 4);
  float*        pcntB = (float*)alloc(NGRAPH * 4);
  const size_t poolBytes = off - poolStart;

  const float* xs[2]   = {xA, xB};
  const int*   eis[2]  = {eiA, eiB};
  const float* eas[2]  = {eaA, eaB};
  const int*   bats[2] = {batA, batB};
  float*        psums[2] = {psumA, psumB};
  unsigned int* pmaxs[2] = {pmaxA, pmaxB};
  float*        pcnts[2] = {pcntA, pcntB};

  hipMemsetAsync(psumA, 0, poolBytes, stream);  // 0 == encoded -inf for max
  prep_wt_k<<<256, 128, 0, stream>>>(W1l, W1r, wtg1);
  prep_wt_k<<<256, 128, 0, stream>>>(W2l, W2r, wtg2);

  for (int g = 0; g < 2; ++g) {
    const int* src = eis[g];
    const int* dst = eis[g] + NE;
    hipMemsetAsync(cnt, 0, (size_t)NN * 4, stream);
    build_k<<<NE / 256, 256, 0, stream>>>(src, dst, eas[g], cnt, bpair, eatt16);
    // layer 1 (fp32 x input)
    node_linear_mfma_k<float><<<dim3((NN + 63) / 64, 2), 256, 0, stream>>>(
        xs[g], wtg1, b1l, b1r, xl16, xr16);
    node_gat_fused_k<<<NN / 8, 256, 0, stream>>>(xl16, xr16, eatt16, bpair, cnt,
                                                 W1e, att1, bias1, h16);
    // layer 2 (fp16 h input, standard layout)
    node_linear_mfma_k<_Float16><<<dim3((NN + 63) / 64, 2), 256, 0, stream>>>(
        h16, wtg2, b2l, b2r, xl16, xr16);
    node_gat_fused_k<<<NN / 8, 256, 0, stream>>>(xl16, xr16, eatt16, bpair, cnt,
                                                 W2e, att2, bias2, h16);
    // pooling
    pool_k<<<(NN + 63) / 64, 128, 0, stream>>>(h16, bats[g], psums[g], pmaxs[g], pcnts[g]);
  }
  head_k<<<NGRAPH, 128, 0, stream>>>(psumA, pmaxA, pcntA, psumB, pmaxB, pcntB,
                                     Wf1, bf1, Wf2, bf2, (float*)d_out);
}

// Round 10
// 806.073 us; speedup vs baseline: 1.1984x; 1.0326x over previous
//
#include <hip/hip_runtime.h>
#include <hip/hip_fp16.h>

#define NN 50000
#define NE 800000
#define HIDD 128
#define FEAT_E 16
#define NGRAPH 8
#define CAP 64

typedef __attribute__((ext_vector_type(2))) _Float16 half2_t;
typedef __attribute__((ext_vector_type(8))) _Float16 half8_t;
typedef __attribute__((ext_vector_type(4))) float floatx4;

// Layout note: node_linear's MFMA epilogue computes, for tile t and lane
// arow, output channel oc(t,arow) = arow*8 + t (set by column-ordering the
// staged weight matrix wtg). Lane arow therefore holds channels
// [arow*8, arow*8+8) contiguously -> ONE half8 store in STANDARD layout,
// and the fused kernel's lane l16 owns 8 contiguous same-head channels
// (head = l16>>2). No permutation anywhere else in the pipeline.

// ---- order-preserving float<->uint encoding for atomicMax on floats ----
__device__ __forceinline__ unsigned int fenc(float f) {
  unsigned int u = __float_as_uint(f);
  return (u & 0x80000000u) ? ~u : (u | 0x80000000u);
}
__device__ __forceinline__ float fdec(unsigned int u) {
  if (u == 0u) return 0.0f;
  float f = (u & 0x80000000u) ? __uint_as_float(u & 0x7fffffffu)
                              : __uint_as_float(~u);
  return __builtin_isfinite(f) ? f : 0.0f;
}

__device__ __forceinline__ half8_t splat8(_Float16 v) {
  return (half8_t){v, v, v, v, v, v, v, v};
}
__device__ __forceinline__ half8_t hmax8(half8_t a, half8_t b) {
#if __has_builtin(__builtin_elementwise_max)
  return __builtin_elementwise_max(a, b);
#else
  half8_t r;
#pragma unroll
  for (int i = 0; i < 8; ++i) r[i] = a[i] > b[i] ? a[i] : b[i];
  return r;
#endif
}
__device__ __forceinline__ float dot_att(half8_t lk, half2_t t01, half2_t t23,
                                         half2_t t45, half2_t t67) {
#if __has_builtin(__builtin_amdgcn_fdot2)
  float p = __builtin_amdgcn_fdot2((half2_t){lk[0], lk[1]}, t01, 0.f, false);
  p = __builtin_amdgcn_fdot2((half2_t){lk[2], lk[3]}, t23, p, false);
  p = __builtin_amdgcn_fdot2((half2_t){lk[4], lk[5]}, t45, p, false);
  p = __builtin_amdgcn_fdot2((half2_t){lk[6], lk[7]}, t67, p, false);
  return p;
#else
  float p = 0.f;
  p += (float)lk[0] * (float)t01[0] + (float)lk[1] * (float)t01[1];
  p += (float)lk[2] * (float)t23[0] + (float)lk[3] * (float)t23[1];
  p += (float)lk[4] * (float)t45[0] + (float)lk[5] * (float)t45[1];
  p += (float)lk[6] * (float)t67[0] + (float)lk[7] * (float)t67[1];
  return p;
#endif
}

// ---- prep: wtg[which(2)][r(128)][col(128)] fp16, col = k ^ ((r&7)<<3).
// Row r of the staged matrix holds W[:, oc_src(r)] with
// oc_src(r) = (r&15)*8 + (r>>4)  -> identity output layout (see note above).
__global__ void prep_wt_k(const float* __restrict__ Wl, const float* __restrict__ Wr,
                          _Float16* __restrict__ wtg) {
  const int r = blockIdx.x & 127;
  const int which = blockIdx.x >> 7;
  const int k = threadIdx.x;  // 0..127
  const float* W = which ? Wr : Wl;
  const int oc_src = (r & 15) * 8 + (r >> 4);
  const int col = k ^ ((r & 7) << 3);
  wtg[(which * 128 + r) * 128 + col] = (_Float16)W[k * 128 + oc_src];
}

// ---- A-fragment loaders (fp32 input layer 1, fp16 layer 2) ----
__device__ __forceinline__ half8_t load_a8(const _Float16* p) {
  return *(const half8_t*)p;
}
__device__ __forceinline__ half8_t load_a8(const float* p) {
  const float4 f0 = *(const float4*)p;
  const float4 f1 = *(const float4*)(p + 4);
  return (half8_t){(_Float16)f0.x, (_Float16)f0.y, (_Float16)f0.z, (_Float16)f0.w,
                   (_Float16)f1.x, (_Float16)f1.y, (_Float16)f1.z, (_Float16)f1.w};
}

// ---- node linear via MFMA, LDS-staged swizzled weights ----
// grid (ceil(NN/64), 2): blockIdx.y = 0 -> xl (Wl), 1 -> xr (Wr).
// block 256 = 4 waves; wave = 16 nodes x 128 outs (8 tiles, 32 acc VGPR).
// Epilogue: lane arow stores channels [arow*8, arow*8+8) as one half8.
template <typename TIN>
__global__ __launch_bounds__(256) void node_linear_mfma_k(
    const TIN* __restrict__ x, const _Float16* __restrict__ wtg,
    const float* __restrict__ bl, const float* __restrict__ br,
    _Float16* __restrict__ xl16, _Float16* __restrict__ xr16) {
  __shared__ _Float16 wt[128 * 128];  // 32 KB
  const int tid = threadIdx.x;
  const int which = blockIdx.y;
  const _Float16* wsrc = wtg + which * (128 * 128);
  const float* bias128 = which ? br : bl;
  _Float16* out = which ? xr16 : xl16;
  {
    const half8_t* src = (const half8_t*)wsrc;
    half8_t* dstl = (half8_t*)wt;
#pragma unroll
    for (int it = 0; it < 8; ++it)
      dstl[it * 256 + tid] = src[it * 256 + tid];
  }
  __syncthreads();

  const int wv = tid >> 6, lane = tid & 63;
  const int arow = lane & 15, kq = lane >> 4;
  const int nbase = blockIdx.x * 64 + wv * 16;
  int nload = nbase + arow;
  if (nload >= NN) nload = NN - 1;
  floatx4 acc[8];
#pragma unroll
  for (int t = 0; t < 8; ++t) acc[t] = (floatx4){0.f, 0.f, 0.f, 0.f};
#pragma unroll
  for (int kb = 0; kb < 4; ++kb) {
    const half8_t a = load_a8(x + (size_t)nload * 128 + kb * 32 + kq * 8);
    const int colbase = (kb * 32 + kq * 8) ^ ((arow & 7) << 3);
#pragma unroll
    for (int t = 0; t < 8; ++t) {
      const half8_t b = *(const half8_t*)&wt[(t * 16 + arow) * 128 + colbase];
      acc[t] = __builtin_amdgcn_mfma_f32_16x16x32_f16(a, b, acc[t], 0, 0, 0);
    }
  }
  // lane arow, tile t -> channel arow*8+t; bias is 8 contiguous floats
  const float4 bv0 = *(const float4*)&bias128[arow * 8];
  const float4 bv1 = *(const float4*)&bias128[arow * 8 + 4];
  const float bv[8] = {bv0.x, bv0.y, bv0.z, bv0.w, bv1.x, bv1.y, bv1.z, bv1.w};
#pragma unroll
  for (int i = 0; i < 4; ++i) {
    const int n = nbase + kq * 4 + i;
    if (n < NN) {
      half8_t v;
#pragma unroll
      for (int t = 0; t < 8; ++t) v[t] = (_Float16)(acc[t][i] + bv[t]);
      *(half8_t*)(out + (size_t)n * 128 + arow * 8) = v;
    }
  }
}

// ---- build: in-edge CSR (src,eidx int2) + fp16 edge-attr copy ----
__global__ void build_k(const int* __restrict__ src, const int* __restrict__ dst,
                        const float* __restrict__ eattr,
                        int* __restrict__ cnt, int2* __restrict__ bpair,
                        _Float16* __restrict__ eatt16) {
  const int e = blockIdx.x * blockDim.x + threadIdx.x;
  if (e >= NE) return;
  const float4* ea = (const float4*)(eattr + (size_t)e * FEAT_E);
  const float4 a0 = ea[0], a1 = ea[1], a2 = ea[2], a3 = ea[3];
  half8_t h0 = {(_Float16)a0.x, (_Float16)a0.y, (_Float16)a0.z, (_Float16)a0.w,
                (_Float16)a1.x, (_Float16)a1.y, (_Float16)a1.z, (_Float16)a1.w};
  half8_t h1 = {(_Float16)a2.x, (_Float16)a2.y, (_Float16)a2.z, (_Float16)a2.w,
                (_Float16)a3.x, (_Float16)a3.y, (_Float16)a3.z, (_Float16)a3.w};
  half8_t* eo = (half8_t*)(eatt16 + (size_t)e * FEAT_E);
  eo[0] = h0; eo[1] = h1;
  const int d = dst[e];
  const int pos = atomicAdd(&cnt[d], 1);
  if (pos < CAP) bpair[(size_t)d * CAP + pos] = make_int2(src[e], e);
}

// ---- FUSED per-node GATv2 (R10): R6 structure + depth-2 prefetch ----
// Model test: R6 (12500 blocks, depth-1) = 105us. Two surviving theories:
// (a) CP dispatch ceiling ~119 blocks/us (105 = 12500/119 exactly);
// (b) memory-parallelism bound: per-iter compute ~195ns < gather latency
// ~375ns, so depth-1 prefetch leaves ~180ns stall/iter. R10 keeps the
// proven 12500-block / 1-node-per-wave structure and adds:
//  * depth-2 triple-buffered edge prefetch (loads for iter k+2 issued
//    before compute of iter k; 12 loads in flight/wave). Fully unrolled
//    k=0..7 (T<=8 since CAP=64) -> all set indices compile-time constant
//    (no scratch). Per-k wave-uniform half-tail skip preserved.
//  * parallel prologue: unconditional bpair row load (lane<CAP always
//    in-allocation) + post-arrival index clamp -> cnt || bpair || xr.
//  * bias load moved to epilogue (slot==0 only) to cut live VGPRs.
// If (b): dur -> 80-92us. If (a): dur flat ~105 -> CP-bound confirmed,
// next step is 2-nodes-interleaved per wave.
__global__ __launch_bounds__(256) void node_gat_fused_k(
    const _Float16* __restrict__ xl16, const _Float16* __restrict__ xr16,
    const _Float16* __restrict__ eatt16,
    const int2* __restrict__ bpair, const int* __restrict__ cnt,
    const float* __restrict__ We, const float* __restrict__ att,
    const float* __restrict__ bias, _Float16* __restrict__ hout) {
  __shared__ half8_t WeS[FEAT_E][16];  // WeS[f][q] = We[f][8q..8q+7], 4 KB
  const int tid = threadIdx.x;
  {
    const int f = tid >> 4, q = tid & 15;
    const float4 w0 = ((const float4*)We)[f * 32 + q * 2];
    const float4 w1 = ((const float4*)We)[f * 32 + q * 2 + 1];
    WeS[f][q] = (half8_t){(_Float16)w0.x, (_Float16)w0.y, (_Float16)w0.z, (_Float16)w0.w,
                          (_Float16)w1.x, (_Float16)w1.y, (_Float16)w1.z, (_Float16)w1.w};
  }
  __syncthreads();

  const int wave = tid >> 6, lane = tid & 63;
  const int slot = lane >> 4, l16 = lane & 15;
  const int d = blockIdx.x * 4 + wave;  // grid = NN/4 exactly

  const float4 af0 = ((const float4*)att)[l16 * 2];
  const float4 af1 = ((const float4*)att)[l16 * 2 + 1];
  const half2_t at01 = {(_Float16)af0.x, (_Float16)af0.y};
  const half2_t at23 = {(_Float16)af0.z, (_Float16)af0.w};
  const half2_t at45 = {(_Float16)af1.x, (_Float16)af1.y};
  const half2_t at67 = {(_Float16)af1.z, (_Float16)af1.w};

  // ---- parallel prologue: cnt || bpair-row || xr (3 independent) ----
  int deg = cnt[d];
  int2 myp = bpair[(size_t)d * CAP + lane];  // unconditional (lane < CAP)
  const half8_t xrh = *(const half8_t*)(xr16 + (size_t)d * HIDD + l16 * 8);
  deg = deg < CAP ? deg : CAP;
  // clamp garbage entries (lanes >= deg) to safe in-bounds indices; their
  // contributions are masked to exactly 0 in FINISH_EDGE.
  myp.x = ((unsigned)myp.x < NN) ? myp.x : 0;
  myp.y = ((unsigned)myp.y < NE) ? myp.y : 0;

  float acc0 = 0.f, acc1 = 0.f, acc2 = 0.f, acc3 = 0.f;
  float acc4 = 0.f, acc5 = 0.f, acc6 = 0.f, acc7 = 0.f;
  float den = 0.f;

#define FINISH_EDGE(XL, EM, VALID)                                       \
  {                                                                      \
    half8_t m_ = ((XL) + xrh) + (EM);                                    \
    half8_t lk_ = hmax8(m_, m_ * splat8((_Float16)0.2f));                \
    float p_ = dot_att(lk_, at01, at23, at45, at67);                     \
    p_ += __shfl_xor(p_, 1);                                             \
    p_ += __shfl_xor(p_, 2);                                             \
    const float w_ = (VALID) ? __expf(p_) : 0.f;                         \
    den += w_;                                                           \
    acc0 = fmaf(w_, (float)(XL)[0], acc0);                               \
    acc1 = fmaf(w_, (float)(XL)[1], acc1);                               \
    acc2 = fmaf(w_, (float)(XL)[2], acc2);                               \
    acc3 = fmaf(w_, (float)(XL)[3], acc3);                               \
    acc4 = fmaf(w_, (float)(XL)[4], acc4);                               \
    acc5 = fmaf(w_, (float)(XL)[5], acc5);                               \
    acc6 = fmaf(w_, (float)(XL)[6], acc6);                               \
    acc7 = fmaf(w_, (float)(XL)[7], acc7);                               \
  }

  // triple-buffered pipeline register sets (indices always compile-time)
  half8_t PX0[3], PX1[3], PA0[3], PB0[3], PA1[3], PB1[3];

#define LOADSET(S, K)                                                    \
  {                                                                      \
    const int eA_ = slot + 8 * (K), eB_ = slot + 4 + 8 * (K);            \
    const int sA_ = __shfl(myp.x, eA_), iA_ = __shfl(myp.y, eA_);        \
    const int sB_ = __shfl(myp.x, eB_), iB_ = __shfl(myp.y, eB_);        \
    PX0[S] = *(const half8_t*)(xl16 + (unsigned)sA_ * 128u + l16 * 8);   \
    PX1[S] = *(const half8_t*)(xl16 + (unsigned)sB_ * 128u + l16 * 8);   \
    PA0[S] = *(const half8_t*)(eatt16 + (unsigned)iA_ * 16u);            \
    PB0[S] = *(const half8_t*)(eatt16 + (unsigned)iA_ * 16u + 8u);       \
    PA1[S] = *(const half8_t*)(eatt16 + (unsigned)iB_ * 16u);            \
    PB1[S] = *(const half8_t*)(eatt16 + (unsigned)iB_ * 16u + 8u);       \
  }

#define COMPUTE_K(S, K)                                                  \
  {                                                                      \
    const int e0_ = slot + 8 * (K);                                      \
    if (8 * (K) + 4 < deg) {  /* full pair, wave-uniform */              \
      const int e1_ = e0_ + 4;                                           \
      half8_t em0 = {}, em1 = {};                                        \
      _Pragma("unroll") for (int f = 0; f < 8; ++f) {                    \
        const half8_t wf = WeS[f][l16];                                  \
        em0 += splat8(PA0[S][f]) * wf;                                   \
        em1 += splat8(PA1[S][f]) * wf;                                   \
      }                                                                  \
      _Pragma("unroll") for (int f = 0; f < 8; ++f) {                    \
        const half8_t wf = WeS[8 + f][l16];                              \
        em0 += splat8(PB0[S][f]) * wf;                                   \
        em1 += splat8(PB1[S][f]) * wf;                                   \
      }                                                                  \
      FINISH_EDGE(PX0[S], em0, e0_ < deg)                                \
      FINISH_EDGE(PX1[S], em1, e1_ < deg)                                \
    } else {  /* remainder <= 4: half-cost body */                       \
      half8_t em0 = {};                                                  \
      _Pragma("unroll") for (int f = 0; f < 8; ++f)                      \
        em0 += splat8(PA0[S][f]) * WeS[f][l16];                          \
      _Pragma("unroll") for (int f = 0; f < 8; ++f)                      \
        em0 += splat8(PB0[S][f]) * WeS[8 + f][l16];                      \
      FINISH_EDGE(PX0[S], em0, e0_ < deg)                                \
    }                                                                    \
  }

  const int T = (deg + 7) >> 3;  // pair-iterations, 0..8
  if (T > 0) LOADSET(0, 0)
  if (T > 1) LOADSET(1, 1)
#pragma unroll
  for (int k = 0; k < 8; ++k) {
    if (k < T) {
      if (k + 2 < T) {
        // issue iter k+2's 6 gathers BEFORE computing iter k (depth-2)
        switch ((k + 2) % 3) {
          case 0: LOADSET(0, k + 2) break;
          case 1: LOADSET(1, k + 2) break;
          default: LOADSET(2, k + 2) break;
        }
      }
      switch (k % 3) {
        case 0: COMPUTE_K(0, k) break;
        case 1: COMPUTE_K(1, k) break;
        default: COMPUTE_K(2, k) break;
      }
    }
  }
#undef COMPUTE_K
#undef LOADSET
#undef FINISH_EDGE

  // combine 4 slots
#define RED(A) A += __shfl_xor(A, 16); A += __shfl_xor(A, 32);
  RED(acc0) RED(acc1) RED(acc2) RED(acc3)
  RED(acc4) RED(acc5) RED(acc6) RED(acc7)
  RED(den)
#undef RED
  if (slot == 0) {
    const float4 b0 = ((const float4*)bias)[l16 * 2];
    const float4 b1 = ((const float4*)bias)[l16 * 2 + 1];
    const float inv = 1.f / (den + 1e-16f);
    float o0 = fmaf(acc0, inv, b0.x), o1 = fmaf(acc1, inv, b0.y);
    float o2 = fmaf(acc2, inv, b0.z), o3 = fmaf(acc3, inv, b0.w);
    float o4 = fmaf(acc4, inv, b1.x), o5 = fmaf(acc5, inv, b1.y);
    float o6 = fmaf(acc6, inv, b1.z), o7 = fmaf(acc7, inv, b1.w);
    o0 = o0 > 0.f ? o0 : expm1f(o0);  o1 = o1 > 0.f ? o1 : expm1f(o1);
    o2 = o2 > 0.f ? o2 : expm1f(o2);  o3 = o3 > 0.f ? o3 : expm1f(o3);
    o4 = o4 > 0.f ? o4 : expm1f(o4);  o5 = o5 > 0.f ? o5 : expm1f(o5);
    o6 = o6 > 0.f ? o6 : expm1f(o6);  o7 = o7 > 0.f ? o7 : expm1f(o7);
    half8_t ho = {(_Float16)o0, (_Float16)o1, (_Float16)o2, (_Float16)o3,
                  (_Float16)o4, (_Float16)o5, (_Float16)o6, (_Float16)o7};
    *(half8_t*)(hout + (size_t)d * HIDD + l16 * 8) = ho;
  }
}

// ---- graph pooling (fp16 h, standard layout) ----
__global__ void pool_k(const _Float16* __restrict__ h, const int* __restrict__ batch,
                       float* __restrict__ gsum, unsigned int* __restrict__ gmax,
                       float* __restrict__ gcnt) {
  __shared__ float ssum[NGRAPH][HIDD];
  __shared__ float smax[NGRAPH][HIDD];
  __shared__ float scnt[NGRAPH];
  const int t = threadIdx.x;
#pragma unroll
  for (int g = 0; g < NGRAPH; ++g) {
    ssum[g][t] = 0.f;
    smax[g][t] = -3.0e38f;
  }
  if (t < NGRAPH) scnt[t] = 0.f;
  __syncthreads();
  const int n0 = blockIdx.x * 64;
  const int nEnd = (n0 + 64 < NN) ? (n0 + 64) : NN;
  unsigned int seen = 0;
  for (int n = n0; n < nEnd; ++n) {
    const int g = batch[n];
    seen |= 1u << g;
    const float v = (float)h[(size_t)n * HIDD + t];
    ssum[g][t] += v;
    smax[g][t] = fmaxf(smax[g][t], v);
    if (t == 0) scnt[g] += 1.f;
  }
  __syncthreads();
  for (int g = 0; g < NGRAPH; ++g) {
    if (seen & (1u << g)) {
      atomicAdd(&gsum[g * HIDD + t], ssum[g][t]);
      atomicMax(&gmax[g * HIDD + t], fenc(smax[g][t]));
      if (t == 0) atomicAdd(&gcnt[g], scnt[g]);
    }
  }
}

// ---- FC head ----
__global__ void head_k(const float* __restrict__ suma, const unsigned int* __restrict__ maxa,
                       const float* __restrict__ cnta,
                       const float* __restrict__ sumb, const unsigned int* __restrict__ maxb,
                       const float* __restrict__ cntb,
                       const float* __restrict__ Wf1, const float* __restrict__ bf1,
                       const float* __restrict__ Wf2, const float* __restrict__ bf2,
                       float* __restrict__ out) {
  __shared__ float c[4 * HIDD];
  __shared__ float red[HIDD];
  const int g = blockIdx.x, t = threadIdx.x;  // 128 threads
  const float ca = fmaxf(cnta[g], 1.f), cb = fmaxf(cntb[g], 1.f);
  c[t]            = suma[g * HIDD + t] / ca;
  c[HIDD + t]     = fdec(maxa[g * HIDD + t]);
  c[2 * HIDD + t] = sumb[g * HIDD + t] / cb;
  c[3 * HIDD + t] = fdec(maxb[g * HIDD + t]);
  __syncthreads();
  float acc = bf1[t];
  for (int i = 0; i < 4 * HIDD; ++i)
    acc = fmaf(c[i], Wf1[(size_t)i * HIDD + t], acc);
  acc = fmaxf(acc, 0.f);
  red[t] = acc * Wf2[t];
  __syncthreads();
  for (int s2 = 64; s2 > 0; s2 >>= 1) {
    if (t < s2) red[t] += red[t + s2];
    __syncthreads();
  }
  if (t == 0) out[g] = 1.f / (1.f + expf(-(red[0] + bf2[0])));
}

extern "C" void kernel_launch(void* const* d_in, const int* in_sizes, int n_in,
                              void* d_out, int out_size, void* d_ws, size_t ws_size,
                              hipStream_t stream) {
  (void)in_sizes; (void)n_in; (void)out_size; (void)ws_size;
  const float* xA    = (const float*)d_in[0];
  const int*   eiA   = (const int*)  d_in[1];
  const float* eaA   = (const float*)d_in[2];
  const int*   batA  = (const int*)  d_in[3];
  const float* xB    = (const float*)d_in[4];
  const int*   eiB   = (const int*)  d_in[5];
  const float* eaB   = (const float*)d_in[6];
  const int*   batB  = (const int*)  d_in[7];
  const float* W1l   = (const float*)d_in[8];
  const float* b1l   = (const float*)d_in[9];
  const float* W1r   = (const float*)d_in[10];
  const float* b1r   = (const float*)d_in[11];
  const float* W1e   = (const float*)d_in[12];
  const float* att1  = (const float*)d_in[13];
  const float* bias1 = (const float*)d_in[14];
  const float* W2l   = (const float*)d_in[15];
  const float* b2l   = (const float*)d_in[16];
  const float* W2r   = (const float*)d_in[17];
  const float* b2r   = (const float*)d_in[18];
  const float* W2e   = (const float*)d_in[19];
  const float* att2  = (const float*)d_in[20];
  const float* bias2 = (const float*)d_in[21];
  const float* Wf1   = (const float*)d_in[22];
  const float* bf1   = (const float*)d_in[23];
  const float* Wf2   = (const float*)d_in[24];
  const float* bf2   = (const float*)d_in[25];

  char* ws = (char*)d_ws;
  size_t off = 0;
  auto alloc = [&](size_t bytes) -> void* {
    void* p = ws + off;
    off += (bytes + 255) & ~(size_t)255;
    return p;
  };
  _Float16* h16    = (_Float16*)alloc((size_t)NN * HIDD * 2);
  _Float16* xl16   = (_Float16*)alloc((size_t)NN * HIDD * 2);
  _Float16* xr16   = (_Float16*)alloc((size_t)NN * HIDD * 2);
  int2*     bpair  = (int2*)    alloc((size_t)NN * CAP * 8);
  _Float16* eatt16 = (_Float16*)alloc((size_t)NE * FEAT_E * 2);
  int*      cnt    = (int*)     alloc((size_t)NN * 4);
  _Float16* wtg1   = (_Float16*)alloc(2 * 128 * 128 * 2);
  _Float16* wtg2   = (_Float16*)alloc(2 * 128 * 128 * 2);
  const size_t poolStart = off;
  float*        psumA = (float*)alloc(NGRAPH * HIDD * 4);
  unsigned int* pmaxA = (unsigned int*)alloc(NGRAPH * HIDD * 4);
  float*        pcntA = (float*)alloc(NGRAPH * 4);
  float*        psumB = (float*)alloc(NGRAPH * HIDD * 4);
  unsigned int* pmaxB = (unsigned int*)alloc(NGRAPH * HIDD * 4);
  float*        pcntB = (float*)alloc(NGRAPH * 4);
  const size_t poolBytes = off - poolStart;

  const float* xs[2]   = {xA, xB};
  const int*   eis[2]  = {eiA, eiB};
  const float* eas[2]  = {eaA, eaB};
  const int*   bats[2] = {batA, batB};
  float*        psums[2] = {psumA, psumB};
  unsigned int* pmaxs[2] = {pmaxA, pmaxB};
  float*        pcnts[2] = {pcntA, pcntB};

  hipMemsetAsync(psumA, 0, poolBytes, stream);  // 0 == encoded -inf for max
  prep_wt_k<<<256, 128, 0, stream>>>(W1l, W1r, wtg1);
  prep_wt_k<<<256, 128, 0, stream>>>(W2l, W2r, wtg2);

  for (int g = 0; g < 2; ++g) {
    const int* src = eis[g];
    const int* dst = eis[g] + NE;
    hipMemsetAsync(cnt, 0, (size_t)NN * 4, stream);
    build_k<<<NE / 256, 256, 0, stream>>>(src, dst, eas[g], cnt, bpair, eatt16);
    // layer 1 (fp32 x input)
    node_linear_mfma_k<float><<<dim3((NN + 63) / 64, 2), 256, 0, stream>>>(
        xs[g], wtg1, b1l, b1r, xl16, xr16);
    node_gat_fused_k<<<NN / 4, 256, 0, stream>>>(xl16, xr16, eatt16, bpair, cnt,
                                                 W1e, att1, bias1, h16);
    // layer 2 (fp16 h input, standard layout)
    node_linear_mfma_k<_Float16><<<dim3((NN + 63) / 64, 2), 256, 0, stream>>>(
        h16, wtg2, b2l, b2r, xl16, xr16);
    node_gat_fused_k<<<NN / 4, 256, 0, stream>>>(xl16, xr16, eatt16, bpair, cnt,
                                                 W2e, att2, bias2, h16);
    // pooling
    pool_k<<<(NN + 63) / 64, 128, 0, stream>>>(h16, bats[g], psums[g], pmaxs[g], pcnts[g]);
  }
  head_k<<<NGRAPH, 128, 0, stream>>>(psumA, pmaxA, pcntA, psumB, pmaxB, pcntB,
                                     Wf1, bf1, Wf2, bf2, (float*)d_out);
}

// Round 13
// 764.359 us; speedup vs baseline: 1.2638x; 1.0546x over previous
//
#include <hip/hip_runtime.h>
#include <hip/hip_fp16.h>

#define NN 50000
#define NE 800000
#define HIDD 128
#define FEAT_E 16
#define NGRAPH 8
#define CAP 64

typedef __attribute__((ext_vector_type(2))) _Float16 half2_t;
typedef __attribute__((ext_vector_type(8))) _Float16 half8_t;
typedef __attribute__((ext_vector_type(4))) float floatx4;

// Layout note: node_linear's MFMA epilogue computes, for tile t and lane
// arow, output channel oc(t,arow) = arow*8 + t (set by column-ordering the
// staged weight matrix wtg). Lane arow therefore holds channels
// [arow*8, arow*8+8) contiguously -> ONE half8 store in STANDARD layout,
// and the fused kernel's lane l16 owns 8 contiguous same-head channels
// (head = l16>>2). No permutation anywhere else in the pipeline.

// ---- order-preserving float<->uint encoding for atomicMax on floats ----
__device__ __forceinline__ unsigned int fenc(float f) {
  unsigned int u = __float_as_uint(f);
  return (u & 0x80000000u) ? ~u : (u | 0x80000000u);
}
__device__ __forceinline__ float fdec(unsigned int u) {
  if (u == 0u) return 0.0f;
  float f = (u & 0x80000000u) ? __uint_as_float(u & 0x7fffffffu)
                              : __uint_as_float(~u);
  return __builtin_isfinite(f) ? f : 0.0f;
}

__device__ __forceinline__ half8_t splat8(_Float16 v) {
  return (half8_t){v, v, v, v, v, v, v, v};
}
__device__ __forceinline__ half8_t hmax8(half8_t a, half8_t b) {
#if __has_builtin(__builtin_elementwise_max)
  return __builtin_elementwise_max(a, b);
#else
  half8_t r;
#pragma unroll
  for (int i = 0; i < 8; ++i) r[i] = a[i] > b[i] ? a[i] : b[i];
  return r;
#endif
}
__device__ __forceinline__ float dot_att(half8_t lk, half2_t t01, half2_t t23,
                                         half2_t t45, half2_t t67) {
#if __has_builtin(__builtin_amdgcn_fdot2)
  float p = __builtin_amdgcn_fdot2((half2_t){lk[0], lk[1]}, t01, 0.f, false);
  p = __builtin_amdgcn_fdot2((half2_t){lk[2], lk[3]}, t23, p, false);
  p = __builtin_amdgcn_fdot2((half2_t){lk[4], lk[5]}, t45, p, false);
  p = __builtin_amdgcn_fdot2((half2_t){lk[6], lk[7]}, t67, p, false);
  return p;
#else
  float p = 0.f;
  p += (float)lk[0] * (float)t01[0] + (float)lk[1] * (float)t01[1];
  p += (float)lk[2] * (float)t23[0] + (float)lk[3] * (float)t23[1];
  p += (float)lk[4] * (float)t45[0] + (float)lk[5] * (float)t45[1];
  p += (float)lk[6] * (float)t67[0] + (float)lk[7] * (float)t67[1];
  return p;
#endif
}

// ---- prep: wtg[which(2)][r(128)][col(128)] fp16, col = k ^ ((r&7)<<3).
// Row r of the staged matrix holds W[:, oc_src(r)] with
// oc_src(r) = (r&15)*8 + (r>>4)  -> identity output layout (see note above).
__global__ void prep_wt_k(const float* __restrict__ Wl, const float* __restrict__ Wr,
                          _Float16* __restrict__ wtg) {
  const int r = blockIdx.x & 127;
  const int which = blockIdx.x >> 7;
  const int k = threadIdx.x;  // 0..127
  const float* W = which ? Wr : Wl;
  const int oc_src = (r & 15) * 8 + (r >> 4);
  const int col = k ^ ((r & 7) << 3);
  wtg[(which * 128 + r) * 128 + col] = (_Float16)W[k * 128 + oc_src];
}

// ---- A-fragment loaders (fp32 input layer 1, fp16 layer 2) ----
__device__ __forceinline__ half8_t load_a8(const _Float16* p) {
  return *(const half8_t*)p;
}
__device__ __forceinline__ half8_t load_a8(const float* p) {
  const float4 f0 = *(const float4*)p;
  const float4 f1 = *(const float4*)(p + 4);
  return (half8_t){(_Float16)f0.x, (_Float16)f0.y, (_Float16)f0.z, (_Float16)f0.w,
                   (_Float16)f1.x, (_Float16)f1.y, (_Float16)f1.z, (_Float16)f1.w};
}

// ---- node linear via MFMA, LDS-staged swizzled weights ----
// grid (ceil(NN/64), 2): blockIdx.y = 0 -> xl (Wl), 1 -> xr (Wr).
// block 256 = 4 waves; wave = 16 nodes x 128 outs (8 tiles, 32 acc VGPR).
// Epilogue: lane arow stores channels [arow*8, arow*8+8) as one half8.
template <typename TIN>
__global__ __launch_bounds__(256) void node_linear_mfma_k(
    const TIN* __restrict__ x, const _Float16* __restrict__ wtg,
    const float* __restrict__ bl, const float* __restrict__ br,
    _Float16* __restrict__ xl16, _Float16* __restrict__ xr16) {
  __shared__ _Float16 wt[128 * 128];  // 32 KB
  const int tid = threadIdx.x;
  const int which = blockIdx.y;
  const _Float16* wsrc = wtg + which * (128 * 128);
  const float* bias128 = which ? br : bl;
  _Float16* out = which ? xr16 : xl16;
  {
    const half8_t* src = (const half8_t*)wsrc;
    half8_t* dstl = (half8_t*)wt;
#pragma unroll
    for (int it = 0; it < 8; ++it)
      dstl[it * 256 + tid] = src[it * 256 + tid];
  }
  __syncthreads();

  const int wv = tid >> 6, lane = tid & 63;
  const int arow = lane & 15, kq = lane >> 4;
  const int nbase = blockIdx.x * 64 + wv * 16;
  int nload = nbase + arow;
  if (nload >= NN) nload = NN - 1;
  floatx4 acc[8];
#pragma unroll
  for (int t = 0; t < 8; ++t) acc[t] = (floatx4){0.f, 0.f, 0.f, 0.f};
#pragma unroll
  for (int kb = 0; kb < 4; ++kb) {
    const half8_t a = load_a8(x + (size_t)nload * 128 + kb * 32 + kq * 8);
    const int colbase = (kb * 32 + kq * 8) ^ ((arow & 7) << 3);
#pragma unroll
    for (int t = 0; t < 8; ++t) {
      const half8_t b = *(const half8_t*)&wt[(t * 16 + arow) * 128 + colbase];
      acc[t] = __builtin_amdgcn_mfma_f32_16x16x32_f16(a, b, acc[t], 0, 0, 0);
    }
  }
  // lane arow, tile t -> channel arow*8+t; bias is 8 contiguous floats
  const float4 bv0 = *(const float4*)&bias128[arow * 8];
  const float4 bv1 = *(const float4*)&bias128[arow * 8 + 4];
  const float bv[8] = {bv0.x, bv0.y, bv0.z, bv0.w, bv1.x, bv1.y, bv1.z, bv1.w};
#pragma unroll
  for (int i = 0; i < 4; ++i) {
    const int n = nbase + kq * 4 + i;
    if (n < NN) {
      half8_t v;
#pragma unroll
      for (int t = 0; t < 8; ++t) v[t] = (_Float16)(acc[t][i] + bv[t]);
      *(half8_t*)(out + (size_t)n * 128 + arow * 8) = v;
    }
  }
}

// ---- build: in-edge CSR (src,eidx int2) + fp16 edge-attr copy ----
__global__ void build_k(const int* __restrict__ src, const int* __restrict__ dst,
                        const float* __restrict__ eattr,
                        int* __restrict__ cnt, int2* __restrict__ bpair,
                        _Float16* __restrict__ eatt16) {
  const int e = blockIdx.x * blockDim.x + threadIdx.x;
  if (e >= NE) return;
  const float4* ea = (const float4*)(eattr + (size_t)e * FEAT_E);
  const float4 a0 = ea[0], a1 = ea[1], a2 = ea[2], a3 = ea[3];
  half8_t h0 = {(_Float16)a0.x, (_Float16)a0.y, (_Float16)a0.z, (_Float16)a0.w,
                (_Float16)a1.x, (_Float16)a1.y, (_Float16)a1.z, (_Float16)a1.w};
  half8_t h1 = {(_Float16)a2.x, (_Float16)a2.y, (_Float16)a2.z, (_Float16)a2.w,
                (_Float16)a3.x, (_Float16)a3.y, (_Float16)a3.z, (_Float16)a3.w};
  half8_t* eo = (half8_t*)(eatt16 + (size_t)e * FEAT_E);
  eo[0] = h0; eo[1] = h1;
  const int d = dst[e];
  const int pos = atomicAdd(&cnt[d], 1);
  if (pos < CAP) bpair[(size_t)d * CAP + pos] = make_int2(src[e], e);
}

// ---- FUSED per-node GATv2 (R11): R6 structure + depth-2, straight-line ----
// R10 post-mortem: switch-based buffer rotation let the compiler sink the
// prefetch loads (VGPR 68 < R6's 84 proves buffers were never live) ->
// the depth-2 experiment never executed; dur regressed to 123.5us from
// branch overhead. R11 re-runs it with token-pasted NAMED buffer sets
// (x0_0..b1_2) and straight-line macro-generated iterations: per k,
// { if(k+2<T) LOADSET_{(k+2)%3}; COMPUTE_{k%3} } in one basic block, so
// 12 loads stay in flight and waits are counted vmcnt. CODGEN GATE:
// VGPR must land ~105-120; if <=85 the compiler defeated it again.
// If MLP-bound: dur 105 -> 85-95. If CP-bound: flat ~105 (conclusive).
__global__ __launch_bounds__(256) void node_gat_fused_k(
    const _Float16* __restrict__ xl16, const _Float16* __restrict__ xr16,
    const _Float16* __restrict__ eatt16,
    const int2* __restrict__ bpair, const int* __restrict__ cnt,
    const float* __restrict__ We, const float* __restrict__ att,
    const float* __restrict__ bias, _Float16* __restrict__ hout) {
  __shared__ half8_t WeS[FEAT_E][16];  // WeS[f][q] = We[f][8q..8q+7], 4 KB
  const int tid = threadIdx.x;
  {
    const int f = tid >> 4, q = tid & 15;
    const float4 w0 = ((const float4*)We)[f * 32 + q * 2];
    const float4 w1 = ((const float4*)We)[f * 32 + q * 2 + 1];
    WeS[f][q] = (half8_t){(_Float16)w0.x, (_Float16)w0.y, (_Float16)w0.z, (_Float16)w0.w,
                          (_Float16)w1.x, (_Float16)w1.y, (_Float16)w1.z, (_Float16)w1.w};
  }
  __syncthreads();

  const int wave = tid >> 6, lane = tid & 63;
  const int slot = lane >> 4, l16 = lane & 15;
  const int d = blockIdx.x * 4 + wave;  // grid = NN/4 exactly

  const float4 af0 = ((const float4*)att)[l16 * 2];
  const float4 af1 = ((const float4*)att)[l16 * 2 + 1];
  const half2_t at01 = {(_Float16)af0.x, (_Float16)af0.y};
  const half2_t at23 = {(_Float16)af0.z, (_Float16)af0.w};
  const half2_t at45 = {(_Float16)af1.x, (_Float16)af1.y};
  const half2_t at67 = {(_Float16)af1.z, (_Float16)af1.w};

  // ---- parallel prologue: cnt || bpair-row || xr (3 independent) ----
  int deg = cnt[d];
  int2 myp = bpair[(size_t)d * CAP + lane];  // unconditional (lane < CAP)
  const half8_t xrh = *(const half8_t*)(xr16 + (size_t)d * HIDD + l16 * 8);
  deg = deg < CAP ? deg : CAP;
  // clamp garbage entries (lanes >= deg) to safe in-bounds indices; their
  // contributions are masked to exactly 0 in FINISH_EDGE.
  myp.x = ((unsigned)myp.x < NN) ? myp.x : 0;
  myp.y = ((unsigned)myp.y < NE) ? myp.y : 0;

  float acc0 = 0.f, acc1 = 0.f, acc2 = 0.f, acc3 = 0.f;
  float acc4 = 0.f, acc5 = 0.f, acc6 = 0.f, acc7 = 0.f;
  float den = 0.f;

#define FINISH_EDGE(XL, EM, VALID)                                       \
  {                                                                      \
    half8_t m_ = ((XL) + xrh) + (EM);                                    \
    half8_t lk_ = hmax8(m_, m_ * splat8((_Float16)0.2f));                \
    float p_ = dot_att(lk_, at01, at23, at45, at67);                     \
    p_ += __shfl_xor(p_, 1);                                             \
    p_ += __shfl_xor(p_, 2);                                             \
    const float w_ = (VALID) ? __expf(p_) : 0.f;                         \
    den += w_;                                                           \
    acc0 = fmaf(w_, (float)(XL)[0], acc0);                               \
    acc1 = fmaf(w_, (float)(XL)[1], acc1);                               \
    acc2 = fmaf(w_, (float)(XL)[2], acc2);                               \
    acc3 = fmaf(w_, (float)(XL)[3], acc3);                               \
    acc4 = fmaf(w_, (float)(XL)[4], acc4);                               \
    acc5 = fmaf(w_, (float)(XL)[5], acc5);                               \
    acc6 = fmaf(w_, (float)(XL)[6], acc6);                               \
    acc7 = fmaf(w_, (float)(XL)[7], acc7);                               \
  }

  // three NAMED buffer sets (token-pasted; no runtime indexing, no switch)
#define DECL_SET(S) half8_t x0_##S, x1_##S, a0_##S, b0_##S, a1_##S, b1_##S;
  DECL_SET(0) DECL_SET(1) DECL_SET(2)

#define LOADSET(S, K)                                                    \
  {                                                                      \
    const int eA_ = slot + 8 * (K), eB_ = eA_ + 4;                       \
    const int sA_ = __shfl(myp.x, eA_), iA_ = __shfl(myp.y, eA_);        \
    const int sB_ = __shfl(myp.x, eB_), iB_ = __shfl(myp.y, eB_);        \
    x0_##S = *(const half8_t*)(xl16 + (unsigned)sA_ * 128u + l16 * 8);   \
    x1_##S = *(const half8_t*)(xl16 + (unsigned)sB_ * 128u + l16 * 8);   \
    a0_##S = *(const half8_t*)(eatt16 + (unsigned)iA_ * 16u);            \
    b0_##S = *(const half8_t*)(eatt16 + (unsigned)iA_ * 16u + 8u);       \
    a1_##S = *(const half8_t*)(eatt16 + (unsigned)iB_ * 16u);            \
    b1_##S = *(const half8_t*)(eatt16 + (unsigned)iB_ * 16u + 8u);       \
  }

#define COMPUTE_K(S, K)                                                  \
  {                                                                      \
    const int e0_ = slot + 8 * (K);                                      \
    if (8 * (K) + 4 < deg) {  /* full pair, wave-uniform */              \
      const int e1_ = e0_ + 4;                                           \
      half8_t em0 = {}, em1 = {};                                        \
      _Pragma("unroll") for (int f = 0; f < 8; ++f) {                    \
        const half8_t wf = WeS[f][l16];                                  \
        em0 += splat8(a0_##S[f]) * wf;                                   \
        em1 += splat8(a1_##S[f]) * wf;                                   \
      }                                                                  \
      _Pragma("unroll") for (int f = 0; f < 8; ++f) {                    \
        const half8_t wf = WeS[8 + f][l16];                              \
        em0 += splat8(b0_##S[f]) * wf;                                   \
        em1 += splat8(b1_##S[f]) * wf;                                   \
      }                                                                  \
      FINISH_EDGE(x0_##S, em0, e0_ < deg)                                \
      FINISH_EDGE(x1_##S, em1, e1_ < deg)                                \
    } else {  /* remainder <= 4: half-cost body */                       \
      half8_t em0 = {};                                                  \
      _Pragma("unroll") for (int f = 0; f < 8; ++f)                      \
        em0 += splat8(a0_##S[f]) * WeS[f][l16];                          \
      _Pragma("unroll") for (int f = 0; f < 8; ++f)                      \
        em0 += splat8(b0_##S[f]) * WeS[8 + f][l16];                      \
      FINISH_EDGE(x0_##S, em0, e0_ < deg)                                \
    }                                                                    \
  }

// straight-line iteration: load for k+2 (set (k+2)%3), compute k (set k%3)
#define STEP(K, SL, SC)                                                  \
  if ((K) < T) {                                                         \
    if ((K) + 2 < T) LOADSET(SL, (K) + 2)                                \
    COMPUTE_K(SC, K)                                                     \
  }

  const int T = (deg + 7) >> 3;  // pair-iterations, 0..8
  if (T > 0) LOADSET(0, 0)
  if (T > 1) LOADSET(1, 1)
  STEP(0, 2, 0)
  STEP(1, 0, 1)
  STEP(2, 1, 2)
  STEP(3, 2, 0)
  STEP(4, 0, 1)
  STEP(5, 1, 2)
  STEP(6, 2, 0)
  STEP(7, 0, 1)  // k+2=9 > T always; load arm folds away
#undef STEP
#undef COMPUTE_K
#undef LOADSET
#undef DECL_SET
#undef FINISH_EDGE

  // combine 4 slots
#define RED(A) A += __shfl_xor(A, 16); A += __shfl_xor(A, 32);
  RED(acc0) RED(acc1) RED(acc2) RED(acc3)
  RED(acc4) RED(acc5) RED(acc6) RED(acc7)
  RED(den)
#undef RED
  if (slot == 0) {
    const float4 b0 = ((const float4*)bias)[l16 * 2];
    const float4 b1 = ((const float4*)bias)[l16 * 2 + 1];
    const float inv = 1.f / (den + 1e-16f);
    float o0 = fmaf(acc0, inv, b0.x), o1 = fmaf(acc1, inv, b0.y);
    float o2 = fmaf(acc2, inv, b0.z), o3 = fmaf(acc3, inv, b0.w);
    float o4 = fmaf(acc4, inv, b1.x), o5 = fmaf(acc5, inv, b1.y);
    float o6 = fmaf(acc6, inv, b1.z), o7 = fmaf(acc7, inv, b1.w);
    o0 = o0 > 0.f ? o0 : expm1f(o0);  o1 = o1 > 0.f ? o1 : expm1f(o1);
    o2 = o2 > 0.f ? o2 : expm1f(o2);  o3 = o3 > 0.f ? o3 : expm1f(o3);
    o4 = o4 > 0.f ? o4 : expm1f(o4);  o5 = o5 > 0.f ? o5 : expm1f(o5);
    o6 = o6 > 0.f ? o6 : expm1f(o6);  o7 = o7 > 0.f ? o7 : expm1f(o7);
    half8_t ho = {(_Float16)o0, (_Float16)o1, (_Float16)o2, (_Float16)o3,
                  (_Float16)o4, (_Float16)o5, (_Float16)o6, (_Float16)o7};
    *(half8_t*)(hout + (size_t)d * HIDD + l16 * 8) = ho;
  }
}

// ---- graph pooling (fp16 h, standard layout) ----
__global__ void pool_k(const _Float16* __restrict__ h, const int* __restrict__ batch,
                       float* __restrict__ gsum, unsigned int* __restrict__ gmax,
                       float* __restrict__ gcnt) {
  __shared__ float ssum[NGRAPH][HIDD];
  __shared__ float smax[NGRAPH][HIDD];
  __shared__ float scnt[NGRAPH];
  const int t = threadIdx.x;
#pragma unroll
  for (int g = 0; g < NGRAPH; ++g) {
    ssum[g][t] = 0.f;
    smax[g][t] = -3.0e38f;
  }
  if (t < NGRAPH) scnt[t] = 0.f;
  __syncthreads();
  const int n0 = blockIdx.x * 64;
  const int nEnd = (n0 + 64 < NN) ? (n0 + 64) : NN;
  unsigned int seen = 0;
  for (int n = n0; n < nEnd; ++n) {
    const int g = batch[n];
    seen |= 1u << g;
    const float v = (float)h[(size_t)n * HIDD + t];
    ssum[g][t] += v;
    smax[g][t] = fmaxf(smax[g][t], v);
    if (t == 0) scnt[g] += 1.f;
  }
  __syncthreads();
  for (int g = 0; g < NGRAPH; ++g) {
    if (seen & (1u << g)) {
      atomicAdd(&gsum[g * HIDD + t], ssum[g][t]);
      atomicMax(&gmax[g * HIDD + t], fenc(smax[g][t]));
      if (t == 0) atomicAdd(&gcnt[g], scnt[g]);
    }
  }
}

// ---- FC head ----
__global__ void head_k(const float* __restrict__ suma, const unsigned int* __restrict__ maxa,
                       const float* __restrict__ cnta,
                       const float* __restrict__ sumb, const unsigned int* __restrict__ maxb,
                       const float* __restrict__ cntb,
                       const float* __restrict__ Wf1, const float* __restrict__ bf1,
                       const float* __restrict__ Wf2, const float* __restrict__ bf2,
                       float* __restrict__ out) {
  __shared__ float c[4 * HIDD];
  __shared__ float red[HIDD];
  const int g = blockIdx.x, t = threadIdx.x;  // 128 threads
  const float ca = fmaxf(cnta[g], 1.f), cb = fmaxf(cntb[g], 1.f);
  c[t]            = suma[g * HIDD + t] / ca;
  c[HIDD + t]     = fdec(maxa[g * HIDD + t]);
  c[2 * HIDD + t] = sumb[g * HIDD + t] / cb;
  c[3 * HIDD + t] = fdec(maxb[g * HIDD + t]);
  __syncthreads();
  float acc = bf1[t];
  for (int i = 0; i < 4 * HIDD; ++i)
    acc = fmaf(c[i], Wf1[(size_t)i * HIDD + t], acc);
  acc = fmaxf(acc, 0.f);
  red[t] = acc * Wf2[t];
  __syncthreads();
  for (int s2 = 64; s2 > 0; s2 >>= 1) {
    if (t < s2) red[t] += red[t + s2];
    __syncthreads();
  }
  if (t == 0) out[g] = 1.f / (1.f + expf(-(red[0] + bf2[0])));
}

extern "C" void kernel_launch(void* const* d_in, const int* in_sizes, int n_in,
                              void* d_out, int out_size, void* d_ws, size_t ws_size,
                              hipStream_t stream) {
  (void)in_sizes; (void)n_in; (void)out_size; (void)ws_size;
  const float* xA    = (const float*)d_in[0];
  const int*   eiA   = (const int*)  d_in[1];
  const float* eaA   = (const float*)d_in[2];
  const int*   batA  = (const int*)  d_in[3];
  const float* xB    = (const float*)d_in[4];
  const int*   eiB   = (const int*)  d_in[5];
  const float* eaB   = (const float*)d_in[6];
  const int*   batB  = (const int*)  d_in[7];
  const float* W1l   = (const float*)d_in[8];
  const float* b1l   = (const float*)d_in[9];
  const float* W1r   = (const float*)d_in[10];
  const float* b1r   = (const float*)d_in[11];
  const float* W1e   = (const float*)d_in[12];
  const float* att1  = (const float*)d_in[13];
  const float* bias1 = (const float*)d_in[14];
  const float* W2l   = (const float*)d_in[15];
  const float* b2l   = (const float*)d_in[16];
  const float* W2r   = (const float*)d_in[17];
  const float* b2r   = (const float*)d_in[18];
  const float* W2e   = (const float*)d_in[19];
  const float* att2  = (const float*)d_in[20];
  const float* bias2 = (const float*)d_in[21];
  const float* Wf1   = (const float*)d_in[22];
  const float* bf1   = (const float*)d_in[23];
  const float* Wf2   = (const float*)d_in[24];
  const float* bf2   = (const float*)d_in[25];

  char* ws = (char*)d_ws;
  size_t off = 0;
  auto alloc = [&](size_t bytes) -> void* {
    void* p = ws + off;
    off += (bytes + 255) & ~(size_t)255;
    return p;
  };
  _Float16* h16    = (_Float16*)alloc((size_t)NN * HIDD * 2);
  _Float16* xl16   = (_Float16*)alloc((size_t)NN * HIDD * 2);
  _Float16* xr16   = (_Float16*)alloc((size_t)NN * HIDD * 2);
  int2*     bpair  = (int2*)    alloc((size_t)NN * CAP * 8);
  _Float16* eatt16 = (_Float16*)alloc((size_t)NE * FEAT_E * 2);
  int*      cnt    = (int*)     alloc((size_t)NN * 4);
  _Float16* wtg1   = (_Float16*)alloc(2 * 128 * 128 * 2);
  _Float16* wtg2   = (_Float16*)alloc(2 * 128 * 128 * 2);
  const size_t poolStart = off;
  float*        psumA = (float*)alloc(NGRAPH * HIDD * 4);
  unsigned int* pmaxA = (unsigned int*)alloc(NGRAPH * HIDD * 4);
  float*        pcntA = (float*)alloc(NGRAPH * 4);
  float*        psumB = (float*)alloc(NGRAPH * HIDD * 4);
  unsigned int* pmaxB = (unsigned int*)alloc(NGRAPH * HIDD * 4);
  float*        pcntB = (float*)alloc(NGRAPH * 4);
  const size_t poolBytes = off - poolStart;

  const float* xs[2]   = {xA, xB};
  const int*   eis[2]  = {eiA, eiB};
  const float* eas[2]  = {eaA, eaB};
  const int*   bats[2] = {batA, batB};
  float*        psums[2] = {psumA, psumB};
  unsigned int* pmaxs[2] = {pmaxA, pmaxB};
  float*        pcnts[2] = {pcntA, pcntB};

  hipMemsetAsync(psumA, 0, poolBytes, stream);  // 0 == encoded -inf for max
  prep_wt_k<<<256, 128, 0, stream>>>(W1l, W1r, wtg1);
  prep_wt_k<<<256, 128, 0, stream>>>(W2l, W2r, wtg2);

  for (int g = 0; g < 2; ++g) {
    const int* src = eis[g];
    const int* dst = eis[g] + NE;
    hipMemsetAsync(cnt, 0, (size_t)NN * 4, stream);
    build_k<<<NE / 256, 256, 0, stream>>>(src, dst, eas[g], cnt, bpair, eatt16);
    // layer 1 (fp32 x input)
    node_linear_mfma_k<float><<<dim3((NN + 63) / 64, 2), 256, 0, stream>>>(
        xs[g], wtg1, b1l, b1r, xl16, xr16);
    node_gat_fused_k<<<NN / 4, 256, 0, stream>>>(xl16, xr16, eatt16, bpair, cnt,
                                                 W1e, att1, bias1, h16);
    // layer 2 (fp16 h input, standard layout)
    node_linear_mfma_k<_Float16><<<dim3((NN + 63) / 64, 2), 256, 0, stream>>>(
        h16, wtg2, b2l, b2r, xl16, xr16);
    node_gat_fused_k<<<NN / 4, 256, 0, stream>>>(xl16, xr16, eatt16, bpair, cnt,
                                                 W2e, att2, bias2, h16);
    // pooling
    pool_k<<<(NN + 63) / 64, 128, 0, stream>>>(h16, bats[g], psums[g], pmaxs[g], pcnts[g]);
  }
  head_k<<<NGRAPH, 128, 0, stream>>>(psumA, pmaxA, pcntA, psumB, pmaxB, pcntB,
                                     Wf1, bf1, Wf2, bf2, (float*)d_out);
}